// Round 5
// baseline (738.653 us; speedup 1.0000x reference)
//
#include <hip/hip_runtime.h>

#define N_NODES 20000
#define N_EDGES 320000
#define ETOT (N_EDGES + N_NODES)
#define G_GROUPS 64

// ---------------- CSR build ----------------

__global__ __launch_bounds__(256) void k_hist(const int* __restrict__ ei, int* __restrict__ counts) {
    int e = blockIdx.x * 256 + threadIdx.x;
    if (e >= ETOT) return;
    int dst = (e < N_EDGES) ? ei[N_EDGES + e] : (e - N_EDGES);
    atomicAdd(&counts[dst], 1);
}

__global__ __launch_bounds__(1024) void k_scan(const int* __restrict__ counts, int* __restrict__ offs,
                                               int* __restrict__ cursor) {
    __shared__ int sdata[1024];
    const int t = threadIdx.x;
    const int chunk = (N_NODES + 1023) / 1024;  // 20
    int base = t * chunk;
    int s = 0;
    for (int i = 0; i < chunk; i++) { int idx = base + i; if (idx < N_NODES) s += counts[idx]; }
    sdata[t] = s;
    __syncthreads();
    for (int off = 1; off < 1024; off <<= 1) {
        int v = (t >= off) ? sdata[t - off] : 0;
        __syncthreads();
        sdata[t] += v;
        __syncthreads();
    }
    int prefix = (t == 0) ? 0 : sdata[t - 1];
    for (int i = 0; i < chunk; i++) {
        int idx = base + i;
        if (idx < N_NODES) {
            int cv = counts[idx];
            offs[idx] = prefix;
            cursor[idx] = prefix;
            prefix += cv;
        }
    }
    if (t == 1023) offs[N_NODES] = sdata[1023];
}

__global__ __launch_bounds__(256) void k_scatter(const int* __restrict__ ei, int* __restrict__ cursor,
                                                 int* __restrict__ csr_src, int* __restrict__ csr_dst) {
    int e = blockIdx.x * 256 + threadIdx.x;
    if (e >= ETOT) return;
    int src = (e < N_EDGES) ? ei[e] : (e - N_EDGES);
    int dst = (e < N_EDGES) ? ei[N_EDGES + e] : (e - N_EDGES);
    int p = atomicAdd(&cursor[dst], 1);
    csr_src[p] = src;
    csr_dst[p] = dst;
}

// ---------------- edge weights ----------------

template <int H>
__global__ __launch_bounds__(256) void k_edgew(const int* __restrict__ csr_src, const int* __restrict__ csr_dst,
                                               const float* __restrict__ alS, const float* __restrict__ alD,
                                               float* __restrict__ wex) {
    int p = blockIdx.x * 256 + threadIdx.x;
    if (p >= ETOT) return;
    int s = csr_src[p], d = csr_dst[p];
    if (H == 4) {
        float4 a = *(const float4*)(alS + s * 4);
        float4 b = *(const float4*)(alD + d * 4);
        float4 v = {a.x + b.x, a.y + b.y, a.z + b.z, a.w + b.w};
        v.x = (v.x > 0.f) ? v.x : 0.2f * v.x;
        v.y = (v.y > 0.f) ? v.y : 0.2f * v.y;
        v.z = (v.z > 0.f) ? v.z : 0.2f * v.z;
        v.w = (v.w > 0.f) ? v.w : 0.2f * v.w;
        float4 w = {__expf(v.x), __expf(v.y), __expf(v.z), __expf(v.w)};
        *(float4*)(wex + p * 4) = w;
    } else {
        float v = alS[s] + alD[d];
        v = (v > 0.f) ? v : 0.2f * v;
        wex[p] = __expf(v);
    }
}

// ---------------- dual GEMM [N,64]x[64,256], 64x64 tiles, alpha fused (strip==head) ----------------

__global__ __launch_bounds__(256) void k_gemm64_dual(const float* __restrict__ x, const float* __restrict__ W1,
                                                     const float* __restrict__ Wr, const float* __restrict__ br,
                                                     const float* __restrict__ a_s, const float* __restrict__ a_d,
                                                     float* __restrict__ h, float* __restrict__ res,
                                                     float* __restrict__ alS, float* __restrict__ alD) {
    const int rb = blockIdx.x >> 2, cs = blockIdx.x & 3;
    const int row0 = rb * 64;
    const int nrows = min(64, N_NODES - row0);
    const int t = threadIdx.x;
    __shared__ float xs[32 * 68];   // A^T [k][r], stride 68
    __shared__ float b1s[32 * 64];  // [k][c]
    __shared__ float brs[32 * 64];
    const int lane = t & 63;
    const int c0 = (t & 15) * 4;
    const int r0 = (t >> 4) * 4;
    // staging map: row index from low lane bits -> 2-way (free) LDS write banks
    const int rl = (t & 15) | ((t >> 6) << 4);  // 0..63
    const int c4 = (t >> 4) & 3;                // float4-col base
    float acc1[4][4] = {}, acc2[4][4] = {};
    for (int k0 = 0; k0 < 64; k0 += 32) {
        if (k0) __syncthreads();
        {
            #pragma unroll
            for (int jj = 0; jj < 2; jj++) {
                int cc = c4 + 4 * jj;  // 0..7
                float4 v = {0.f, 0.f, 0.f, 0.f};
                if (rl < nrows) v = *(const float4*)(x + (row0 + rl) * 64 + k0 + cc * 4);
                xs[(cc * 4 + 0) * 68 + rl] = v.x;
                xs[(cc * 4 + 1) * 68 + rl] = v.y;
                xs[(cc * 4 + 2) * 68 + rl] = v.z;
                xs[(cc * 4 + 3) * 68 + rl] = v.w;
            }
        }
        {
            int cc = (t & 15) * 4;
            int k = t >> 4;
            #pragma unroll
            for (int pass = 0; pass < 2; pass++, k += 16) {
                *(float4*)(b1s + k * 64 + cc) = *(const float4*)(W1 + (k0 + k) * 256 + cs * 64 + cc);
                *(float4*)(brs + k * 64 + cc) = *(const float4*)(Wr + (k0 + k) * 256 + cs * 64 + cc);
            }
        }
        __syncthreads();
        #pragma unroll 8
        for (int k = 0; k < 32; k++) {
            float4 av = *(const float4*)(xs + k * 68 + r0);
            float4 b1 = *(const float4*)(b1s + k * 64 + c0);
            float4 b2 = *(const float4*)(brs + k * 64 + c0);
            float a[4] = {av.x, av.y, av.z, av.w};
            #pragma unroll
            for (int i = 0; i < 4; i++) {
                acc1[i][0] += a[i] * b1.x; acc1[i][1] += a[i] * b1.y;
                acc1[i][2] += a[i] * b1.z; acc1[i][3] += a[i] * b1.w;
                acc2[i][0] += a[i] * b2.x; acc2[i][1] += a[i] * b2.y;
                acc2[i][2] += a[i] * b2.z; acc2[i][3] += a[i] * b2.w;
            }
        }
    }
    const int gcol = cs * 64 + c0;
    float4 bv = *(const float4*)(br + gcol);
    float4 asv = *(const float4*)(a_s + gcol);
    float4 adv = *(const float4*)(a_d + gcol);
    #pragma unroll
    for (int i = 0; i < 4; i++) {
        int gr = row0 + r0 + i;
        bool ok = (r0 + i) < nrows;
        float4 o1 = {acc1[i][0], acc1[i][1], acc1[i][2], acc1[i][3]};
        if (ok) {
            *(float4*)(h + gr * 256 + gcol) = o1;
            float4 o2 = {acc2[i][0] + bv.x, acc2[i][1] + bv.y, acc2[i][2] + bv.z, acc2[i][3] + bv.w};
            *(float4*)(res + gr * 256 + gcol) = o2;
        }
        float ps = o1.x * asv.x + o1.y * asv.y + o1.z * asv.z + o1.w * asv.w;
        float pd = o1.x * adv.x + o1.y * adv.y + o1.z * adv.z + o1.w * adv.w;
        #pragma unroll
        for (int off = 8; off > 0; off >>= 1) {
            ps += __shfl_down(ps, off);
            pd += __shfl_down(pd, off);
        }
        if (((lane & 15) == 0) && ok) {
            alS[gr * 4 + cs] = ps;
            alD[gr * 4 + cs] = pd;
        }
    }
}

// ---------------- standalone attention logits (H=1 path) ----------------

__global__ __launch_bounds__(256) void k_alpha(const float* __restrict__ h, const float* __restrict__ a_s,
                                               const float* __restrict__ a_d, float* __restrict__ alS,
                                               float* __restrict__ alD) {
    int node = blockIdx.x * 4 + (threadIdx.x >> 6);
    int lane = threadIdx.x & 63;
    if (node >= N_NODES) return;
    const float4 hv = *(const float4*)(h + node * 256 + lane * 4);
    const float4 as = *(const float4*)(a_s + lane * 4);
    const float4 ad = *(const float4*)(a_d + lane * 4);
    float ps = hv.x * as.x + hv.y * as.y + hv.z * as.z + hv.w * as.w;
    float pd = hv.x * ad.x + hv.y * ad.y + hv.z * ad.z + hv.w * ad.w;
    #pragma unroll
    for (int off = 32; off > 0; off >>= 1) {
        ps += __shfl_down(ps, off);
        pd += __shfl_down(pd, off);
    }
    if (lane == 0) {
        alS[node] = ps;
        alD[node] = pd;
    }
}

// ---------------- CSR softmax-aggregation ----------------

template <int H>
__global__ __launch_bounds__(256) void k_agg(const float* __restrict__ h, const float* __restrict__ wex,
                                             const int* __restrict__ offs, const int* __restrict__ csr_src,
                                             const float* __restrict__ bias, float* __restrict__ out) {
    int node = blockIdx.x * 4 + (threadIdx.x >> 6);
    int lane = threadIdx.x & 63;
    if (node >= N_NODES) return;
    const int head = (lane * H) >> 6;
    int e0 = offs[node], e1 = offs[node + 1];
    float den = 0.f, a0 = 0.f, a1 = 0.f, a2 = 0.f, a3 = 0.f;
    int e = e0;
    for (; e + 4 <= e1; e += 4) {
        int s0 = csr_src[e], s1 = csr_src[e + 1], s2 = csr_src[e + 2], s3 = csr_src[e + 3];
        float w0 = wex[(e + 0) * H + head];
        float w1 = wex[(e + 1) * H + head];
        float w2 = wex[(e + 2) * H + head];
        float w3 = wex[(e + 3) * H + head];
        const float4 h0 = *(const float4*)(h + s0 * 256 + lane * 4);
        const float4 h1 = *(const float4*)(h + s1 * 256 + lane * 4);
        const float4 h2 = *(const float4*)(h + s2 * 256 + lane * 4);
        const float4 h3 = *(const float4*)(h + s3 * 256 + lane * 4);
        den += (w0 + w1) + (w2 + w3);
        a0 += w0 * h0.x + w1 * h1.x + w2 * h2.x + w3 * h3.x;
        a1 += w0 * h0.y + w1 * h1.y + w2 * h2.y + w3 * h3.y;
        a2 += w0 * h0.z + w1 * h1.z + w2 * h2.z + w3 * h3.z;
        a3 += w0 * h0.w + w1 * h1.w + w2 * h2.w + w3 * h3.w;
    }
    for (; e < e1; e++) {
        int s = csr_src[e];
        float w = wex[e * H + head];
        const float4 hv = *(const float4*)(h + s * 256 + lane * 4);
        den += w;
        a0 += w * hv.x; a1 += w * hv.y; a2 += w * hv.z; a3 += w * hv.w;
    }
    float inv = 1.f / den;
    const float4 bv = *(const float4*)(bias + lane * 4);
    float4 o = {a0 * inv + bv.x, a1 * inv + bv.y, a2 * inv + bv.z, a3 * inv + bv.w};
    *(float4*)(out + node * 256 + lane * 4) = o;
}

// ---------------- BatchNorm stats ----------------

__global__ __launch_bounds__(256) void k_bnstats(const float* __restrict__ x, float* __restrict__ sum,
                                                 float* __restrict__ sumsq) {
    int c = threadIdx.x;
    float s = 0.f, q = 0.f;
    for (int r = blockIdx.x; r < N_NODES; r += gridDim.x) {
        float v = x[r * 256 + c];
        s += v; q += v * v;
    }
    atomicAdd(&sum[c], s);
    atomicAdd(&sumsq[c], q);
}

__global__ __launch_bounds__(256) void k_bnfin(const float* __restrict__ sum, const float* __restrict__ sumsq,
                                               const float* __restrict__ g, const float* __restrict__ be,
                                               float* __restrict__ scale, float* __restrict__ shift) {
    int c = threadIdx.x;
    float mu = sum[c] * (1.f / N_NODES);
    float var = sumsq[c] * (1.f / N_NODES) - mu * mu;
    float sc = g[c] * rsqrtf(var + 1e-5f);
    scale[c] = sc;
    shift[c] = be[c] - mu * sc;
}

// ---------------- GEMM relu(bn(A))@B [N,256]x[256,256], 128x64 tiles, 8x4 thread tile ----------------
// 3 ds_read_b128 per 32 FMA (10.7 FLOP/LDS-float) -> FMA-bound, not LDS-bound.

__global__ __launch_bounds__(256) void k_gemm256(const float* __restrict__ A, const float* __restrict__ scale,
                                                 const float* __restrict__ shift, const float* __restrict__ B,
                                                 float* __restrict__ C) {
    const int rb = blockIdx.x >> 2, cs = blockIdx.x & 3;
    const int row0 = rb * 128;
    const int col0 = cs * 64;
    const int nrows = min(128, N_NODES - row0);
    const int t = threadIdx.x;
    __shared__ float xs[32 * 132];  // A^T [k][r], stride 132 (2-way write banks)
    __shared__ float bs[32 * 64];   // [k][c]
    __shared__ float scs[256], shs[256];
    scs[t] = scale[t];
    shs[t] = shift[t];
    const int rl = (t & 15) | ((t >> 6) << 4);  // 0..63 (row index from low lane bits)
    const int c4 = (t >> 4) & 3;                // float4-col base 0..3
    const int c0 = (t & 15) * 4;                // output cols
    const int r0 = (t >> 4) * 8;                // output rows (8 per thread)
    float acc[8][4] = {};
    for (int k0 = 0; k0 < 256; k0 += 32) {
        __syncthreads();  // first iter also covers scs/shs
        #pragma unroll
        for (int i = 0; i < 2; i++) {
            int r = rl + 64 * i;
            #pragma unroll
            for (int jj = 0; jj < 2; jj++) {
                int cc = c4 + 4 * jj;  // float4-col 0..7
                int kcol = k0 + cc * 4;
                float4 w = {0.f, 0.f, 0.f, 0.f};
                if (r < nrows) {
                    float4 v = *(const float4*)(A + (row0 + r) * 256 + kcol);
                    w.x = fmaxf(v.x * scs[kcol + 0] + shs[kcol + 0], 0.f);
                    w.y = fmaxf(v.y * scs[kcol + 1] + shs[kcol + 1], 0.f);
                    w.z = fmaxf(v.z * scs[kcol + 2] + shs[kcol + 2], 0.f);
                    w.w = fmaxf(v.w * scs[kcol + 3] + shs[kcol + 3], 0.f);
                }
                xs[(cc * 4 + 0) * 132 + r] = w.x;
                xs[(cc * 4 + 1) * 132 + r] = w.y;
                xs[(cc * 4 + 2) * 132 + r] = w.z;
                xs[(cc * 4 + 3) * 132 + r] = w.w;
            }
        }
        {
            int ccB = (t & 15) * 4;
            int kB = t >> 4;
            #pragma unroll
            for (int pass = 0; pass < 2; pass++, kB += 16) {
                *(float4*)(bs + kB * 64 + ccB) = *(const float4*)(B + (k0 + kB) * 256 + col0 + ccB);
            }
        }
        __syncthreads();
        #pragma unroll 8
        for (int k = 0; k < 32; k++) {
            float4 a0 = *(const float4*)(xs + k * 132 + r0);
            float4 a1 = *(const float4*)(xs + k * 132 + r0 + 4);
            float4 bv = *(const float4*)(bs + k * 64 + c0);
            float a[8] = {a0.x, a0.y, a0.z, a0.w, a1.x, a1.y, a1.z, a1.w};
            #pragma unroll
            for (int i = 0; i < 8; i++) {
                acc[i][0] += a[i] * bv.x; acc[i][1] += a[i] * bv.y;
                acc[i][2] += a[i] * bv.z; acc[i][3] += a[i] * bv.w;
            }
        }
    }
    #pragma unroll
    for (int i = 0; i < 8; i++) {
        if ((r0 + i) < nrows) {
            int gr = row0 + r0 + i;
            float4 o = {acc[i][0], acc[i][1], acc[i][2], acc[i][3]};
            *(float4*)(C + gr * 256 + col0 + c0) = o;
        }
    }
}

// ---------------- final GEMM ((relu(bn(A))+res)*invsqrt2)@Wf+bf -> [N,64], 32x64 tiles ----------------

__global__ __launch_bounds__(256) void k_gemm_final(const float* __restrict__ A, const float* __restrict__ scale,
                                                    const float* __restrict__ shift, const float* __restrict__ res,
                                                    const float* __restrict__ B, const float* __restrict__ bias,
                                                    float* __restrict__ y) {
    const int row0 = blockIdx.x * 32;  // 625 blocks, exact
    const int t = threadIdx.x;
    const float INVS = 0.70710678118654752440f;
    __shared__ float xs[32 * 36];  // A^T [k][r], stride 36
    __shared__ float bs[32 * 64];  // [k][c]
    __shared__ float scs[256], shs[256];
    scs[t] = scale[t];
    shs[t] = shift[t];
    const int rf = (t & 15) | ((t >> 7) << 4);  // 0..31
    const int cf = (t >> 4) & 7;                // float4-col 0..7
    const int c0 = (t & 15) * 4;
    const int r0 = (t >> 4) * 2;
    float acc[2][4] = {};
    for (int k0 = 0; k0 < 256; k0 += 32) {
        __syncthreads();
        {
            int kcol = k0 + cf * 4;
            int gi = (row0 + rf) * 256 + kcol;
            float4 v = *(const float4*)(A + gi);
            float4 rv = *(const float4*)(res + gi);
            xs[(cf * 4 + 0) * 36 + rf] = (fmaxf(v.x * scs[kcol + 0] + shs[kcol + 0], 0.f) + rv.x) * INVS;
            xs[(cf * 4 + 1) * 36 + rf] = (fmaxf(v.y * scs[kcol + 1] + shs[kcol + 1], 0.f) + rv.y) * INVS;
            xs[(cf * 4 + 2) * 36 + rf] = (fmaxf(v.z * scs[kcol + 2] + shs[kcol + 2], 0.f) + rv.z) * INVS;
            xs[(cf * 4 + 3) * 36 + rf] = (fmaxf(v.w * scs[kcol + 3] + shs[kcol + 3], 0.f) + rv.w) * INVS;
        }
        {
            int cc = (t & 15) * 4;
            int k = t >> 4;
            #pragma unroll
            for (int pass = 0; pass < 2; pass++, k += 16) {
                *(float4*)(bs + k * 64 + cc) = *(const float4*)(B + (k0 + k) * 64 + cc);
            }
        }
        __syncthreads();
        #pragma unroll 8
        for (int k = 0; k < 32; k++) {
            float2 av = *(const float2*)(xs + k * 36 + r0);
            float4 bv = *(const float4*)(bs + k * 64 + c0);
            acc[0][0] += av.x * bv.x; acc[0][1] += av.x * bv.y;
            acc[0][2] += av.x * bv.z; acc[0][3] += av.x * bv.w;
            acc[1][0] += av.y * bv.x; acc[1][1] += av.y * bv.y;
            acc[1][2] += av.y * bv.z; acc[1][3] += av.y * bv.w;
        }
    }
    float4 bv = *(const float4*)(bias + c0);
    #pragma unroll
    for (int i = 0; i < 2; i++) {
        int gr = row0 + r0 + i;
        float4 o = {acc[i][0] + bv.x, acc[i][1] + bv.y, acc[i][2] + bv.z, acc[i][3] + bv.w};
        *(float4*)(y + gr * 64 + c0) = o;
    }
}

// ---------------- fused mean-pool (sorted batch) + MLP head ----------------

__global__ __launch_bounds__(256) void k_pool_head(const float* __restrict__ x, const int* __restrict__ batch,
                                                   const float* __restrict__ Wh1, const float* __restrict__ bh1,
                                                   const float* __restrict__ Wh2, const float* __restrict__ bh2,
                                                   float* __restrict__ out) {
    const int g = blockIdx.x;
    const int t = threadIdx.x;
    int lo = 0, hi = N_NODES;
    while (lo < hi) { int mid = (lo + hi) >> 1; if (batch[mid] < g) lo = mid + 1; else hi = mid; }
    int start = lo;
    hi = N_NODES;
    while (lo < hi) { int mid = (lo + hi) >> 1; if (batch[mid] < g + 1) lo = mid + 1; else hi = mid; }
    int end = lo;
    float cnt = (float)(end - start);

    __shared__ float part[256];
    __shared__ float p[64];
    __shared__ float hrow[256];
    const int c = t & 63;
    float s = 0.f;
    for (int r = start + (t >> 6); r < end; r += 4) s += x[r * 64 + c];
    part[t] = s;
    __syncthreads();
    if (t < 64) {
        float v = part[t] + part[t + 64] + part[t + 128] + part[t + 192];
        p[t] = v / fmaxf(cnt, 1.f);
    }
    __syncthreads();
    float a = bh1[t];
    #pragma unroll 8
    for (int k = 0; k < 64; k++) a += p[k] * Wh1[k * 256 + t];
    hrow[t] = fmaxf(a, 0.f);
    __syncthreads();
    if (t < 128) {
        float o = bh2[t];
        #pragma unroll 8
        for (int k = 0; k < 256; k++) o += hrow[k] * Wh2[k * 128 + t];
        out[g * 128 + t] = o;
    }
}

// ---------------- host ----------------

extern "C" void kernel_launch(void* const* d_in, const int* in_sizes, int n_in,
                              void* d_out, int out_size, void* d_ws, size_t ws_size,
                              hipStream_t stream) {
    (void)in_sizes; (void)n_in; (void)out_size; (void)ws_size;
    const float* x0 = (const float*)d_in[0];
    const int* ei = (const int*)d_in[1];
    const int* batch = (const int*)d_in[2];
    const float* Wh1 = (const float*)d_in[35];
    const float* bh1 = (const float*)d_in[36];
    const float* Wh2 = (const float*)d_in[37];
    const float* bh2 = (const float*)d_in[38];

    char* p = (char*)d_ws;
    auto alloc = [&](size_t bytes) -> void* {
        void* r = (void*)p;
        p += (bytes + 255) & ~(size_t)255;
        return r;
    };
    int* counts = (int*)alloc((size_t)N_NODES * 4);
    int* offs = (int*)alloc((size_t)(N_NODES + 1) * 4);
    int* cursor = (int*)alloc((size_t)N_NODES * 4);
    int* csr_src = (int*)alloc((size_t)ETOT * 4);
    int* csr_dst = (int*)alloc((size_t)ETOT * 4);
    float* wex = (float*)alloc((size_t)ETOT * 4 * 4);
    float* alS = (float*)alloc((size_t)N_NODES * 4 * 4);
    float* alD = (float*)alloc((size_t)N_NODES * 4 * 4);
    float* bnsum = (float*)alloc(2048);
    float* bnsq = bnsum + 256;
    float* scaleb = (float*)alloc(1024);
    float* shiftb = (float*)alloc(1024);
    float* hbuf = (float*)alloc((size_t)N_NODES * 256 * 4);
    float* obuf = (float*)alloc((size_t)N_NODES * 256 * 4);
    float* rbuf = (float*)alloc((size_t)N_NODES * 256 * 4);
    float* xout = (float*)alloc((size_t)N_NODES * 64 * 4);

    // --- CSR by dst ---
    hipMemsetAsync(counts, 0, (size_t)N_NODES * 4, stream);
    k_hist<<<(ETOT + 255) / 256, 256, 0, stream>>>(ei, counts);
    k_scan<<<1, 1024, 0, stream>>>(counts, offs, cursor);
    k_scatter<<<(ETOT + 255) / 256, 256, 0, stream>>>(ei, cursor, csr_src, csr_dst);

    const int tile64_blocks = ((N_NODES + 63) / 64) * 4;     // 313*4 = 1252
    const int tile128_blocks = ((N_NODES + 127) / 128) * 4;  // 157*4 = 628
    const int node_blocks = (N_NODES + 3) / 4;               // 5000
    const int edge_blocks = (ETOT + 255) / 256;
    const int final_blocks = N_NODES / 32;                   // 625

    auto run_block = [&](const float* xin, int base) {
        const float* W1 = (const float*)d_in[base + 0];
        const float* a1s = (const float*)d_in[base + 1];
        const float* a1d = (const float*)d_in[base + 2];
        const float* b1 = (const float*)d_in[base + 3];
        const float* g1 = (const float*)d_in[base + 4];
        const float* be1 = (const float*)d_in[base + 5];
        const float* W2 = (const float*)d_in[base + 6];
        const float* a2s = (const float*)d_in[base + 7];
        const float* a2d = (const float*)d_in[base + 8];
        const float* b2 = (const float*)d_in[base + 9];
        const float* g2 = (const float*)d_in[base + 10];
        const float* be2 = (const float*)d_in[base + 11];
        const float* Wr = (const float*)d_in[base + 12];
        const float* br = (const float*)d_in[base + 13];
        const float* Wf = (const float*)d_in[base + 14];
        const float* bf = (const float*)d_in[base + 15];

        // h1 = x@W1 ; res = x@Wr + br ; alpha1 fused (strip == head)
        k_gemm64_dual<<<tile64_blocks, 256, 0, stream>>>(xin, W1, Wr, br, a1s, a1d, hbuf, rbuf, alS, alD);
        // GAT1 (H=4)
        k_edgew<4><<<edge_blocks, 256, 0, stream>>>(csr_src, csr_dst, alS, alD, wex);
        k_agg<4><<<node_blocks, 256, 0, stream>>>(hbuf, wex, offs, csr_src, b1, obuf);
        // BN1
        hipMemsetAsync(bnsum, 0, 2048, stream);
        k_bnstats<<<256, 256, 0, stream>>>(obuf, bnsum, bnsq);
        k_bnfin<<<1, 256, 0, stream>>>(bnsum, bnsq, g1, be1, scaleb, shiftb);
        // h2 = relu(bn(out1)) @ W2
        k_gemm256<<<tile128_blocks, 256, 0, stream>>>(obuf, scaleb, shiftb, W2, hbuf);
        // GAT2 (H=1)
        k_alpha<<<node_blocks, 256, 0, stream>>>(hbuf, a2s, a2d, alS, alD);
        k_edgew<1><<<edge_blocks, 256, 0, stream>>>(csr_src, csr_dst, alS, alD, wex);
        k_agg<1><<<node_blocks, 256, 0, stream>>>(hbuf, wex, offs, csr_src, b2, obuf);
        // BN2
        hipMemsetAsync(bnsum, 0, 2048, stream);
        k_bnstats<<<256, 256, 0, stream>>>(obuf, bnsum, bnsq);
        k_bnfin<<<1, 256, 0, stream>>>(bnsum, bnsq, g2, be2, scaleb, shiftb);
        // y = ((relu(bn(out2)) + res) * invsqrt2) @ Wf + bf
        k_gemm_final<<<final_blocks, 256, 0, stream>>>(obuf, scaleb, shiftb, rbuf, Wf, bf, xout);
    };

    run_block(x0, 3);
    run_block(xout, 19);

    // --- fused mean-pool + head ---
    k_pool_head<<<G_GROUPS, 256, 0, stream>>>(xout, batch, Wh1, bh1, Wh2, bh2, (float*)d_out);
}

// Round 8
// 705.663 us; speedup vs baseline: 1.0468x; 1.0468x over previous
//
#include <hip/hip_runtime.h>

#define N_NODES 20000
#define N_EDGES 320000
#define ETOT (N_EDGES + N_NODES)
#define G_GROUPS 64

// ---------------- CSR build ----------------

__global__ __launch_bounds__(256) void k_hist(const int* __restrict__ ei, int* __restrict__ counts) {
    int e = blockIdx.x * 256 + threadIdx.x;
    if (e >= ETOT) return;
    int dst = (e < N_EDGES) ? ei[N_EDGES + e] : (e - N_EDGES);
    atomicAdd(&counts[dst], 1);
}

__global__ __launch_bounds__(1024) void k_scan(const int* __restrict__ counts, int* __restrict__ offs,
                                               int* __restrict__ cursor) {
    __shared__ int sdata[1024];
    const int t = threadIdx.x;
    const int chunk = (N_NODES + 1023) / 1024;  // 20
    int base = t * chunk;
    int s = 0;
    for (int i = 0; i < chunk; i++) { int idx = base + i; if (idx < N_NODES) s += counts[idx]; }
    sdata[t] = s;
    __syncthreads();
    for (int off = 1; off < 1024; off <<= 1) {
        int v = (t >= off) ? sdata[t - off] : 0;
        __syncthreads();
        sdata[t] += v;
        __syncthreads();
    }
    int prefix = (t == 0) ? 0 : sdata[t - 1];
    for (int i = 0; i < chunk; i++) {
        int idx = base + i;
        if (idx < N_NODES) {
            int cv = counts[idx];
            offs[idx] = prefix;
            cursor[idx] = prefix;
            prefix += cv;
        }
    }
    if (t == 1023) offs[N_NODES] = sdata[1023];
}

__global__ __launch_bounds__(256) void k_scatter(const int* __restrict__ ei, int* __restrict__ cursor,
                                                 int* __restrict__ csr_src) {
    int e = blockIdx.x * 256 + threadIdx.x;
    if (e >= ETOT) return;
    int src = (e < N_EDGES) ? ei[e] : (e - N_EDGES);
    int dst = (e < N_EDGES) ? ei[N_EDGES + e] : (e - N_EDGES);
    int p = atomicAdd(&cursor[dst], 1);
    csr_src[p] = src;
}

// ---------------- dual GEMM [N,64]x[64,256], 64x64 tiles, alpha fused (strip==head) ----------------

__global__ __launch_bounds__(256) void k_gemm64_dual(const float* __restrict__ x, const float* __restrict__ W1,
                                                     const float* __restrict__ Wr, const float* __restrict__ br,
                                                     const float* __restrict__ a_s, const float* __restrict__ a_d,
                                                     float* __restrict__ h, float* __restrict__ res,
                                                     float* __restrict__ alS, float* __restrict__ alD) {
    const int rb = blockIdx.x >> 2, cs = blockIdx.x & 3;
    const int row0 = rb * 64;
    const int nrows = min(64, N_NODES - row0);
    const int t = threadIdx.x;
    __shared__ float xs[32 * 68];   // A^T [k][r], stride 68
    __shared__ float b1s[32 * 64];  // [k][c]
    __shared__ float brs[32 * 64];
    const int lane = t & 63;
    const int c0 = (t & 15) * 4;
    const int r0 = (t >> 4) * 4;
    // staging map: row index from low lane bits -> 2-way (free) LDS write banks
    const int rl = (t & 15) | ((t >> 6) << 4);  // 0..63
    const int c4 = (t >> 4) & 3;                // float4-col base
    float acc1[4][4] = {}, acc2[4][4] = {};
    for (int k0 = 0; k0 < 64; k0 += 32) {
        if (k0) __syncthreads();
        {
            #pragma unroll
            for (int jj = 0; jj < 2; jj++) {
                int cc = c4 + 4 * jj;  // 0..7
                float4 v = {0.f, 0.f, 0.f, 0.f};
                if (rl < nrows) v = *(const float4*)(x + (row0 + rl) * 64 + k0 + cc * 4);
                xs[(cc * 4 + 0) * 68 + rl] = v.x;
                xs[(cc * 4 + 1) * 68 + rl] = v.y;
                xs[(cc * 4 + 2) * 68 + rl] = v.z;
                xs[(cc * 4 + 3) * 68 + rl] = v.w;
            }
        }
        {
            int cc = (t & 15) * 4;
            int k = t >> 4;
            #pragma unroll
            for (int pass = 0; pass < 2; pass++, k += 16) {
                *(float4*)(b1s + k * 64 + cc) = *(const float4*)(W1 + (k0 + k) * 256 + cs * 64 + cc);
                *(float4*)(brs + k * 64 + cc) = *(const float4*)(Wr + (k0 + k) * 256 + cs * 64 + cc);
            }
        }
        __syncthreads();
        #pragma unroll 8
        for (int k = 0; k < 32; k++) {
            float4 av = *(const float4*)(xs + k * 68 + r0);
            float4 b1 = *(const float4*)(b1s + k * 64 + c0);
            float4 b2 = *(const float4*)(brs + k * 64 + c0);
            float a[4] = {av.x, av.y, av.z, av.w};
            #pragma unroll
            for (int i = 0; i < 4; i++) {
                acc1[i][0] += a[i] * b1.x; acc1[i][1] += a[i] * b1.y;
                acc1[i][2] += a[i] * b1.z; acc1[i][3] += a[i] * b1.w;
                acc2[i][0] += a[i] * b2.x; acc2[i][1] += a[i] * b2.y;
                acc2[i][2] += a[i] * b2.z; acc2[i][3] += a[i] * b2.w;
            }
        }
    }
    const int gcol = cs * 64 + c0;
    float4 bv = *(const float4*)(br + gcol);
    float4 asv = *(const float4*)(a_s + gcol);
    float4 adv = *(const float4*)(a_d + gcol);
    #pragma unroll
    for (int i = 0; i < 4; i++) {
        int gr = row0 + r0 + i;
        bool ok = (r0 + i) < nrows;
        float4 o1 = {acc1[i][0], acc1[i][1], acc1[i][2], acc1[i][3]};
        if (ok) {
            *(float4*)(h + gr * 256 + gcol) = o1;
            float4 o2 = {acc2[i][0] + bv.x, acc2[i][1] + bv.y, acc2[i][2] + bv.z, acc2[i][3] + bv.w};
            *(float4*)(res + gr * 256 + gcol) = o2;
        }
        float ps = o1.x * asv.x + o1.y * asv.y + o1.z * asv.z + o1.w * asv.w;
        float pd = o1.x * adv.x + o1.y * adv.y + o1.z * adv.z + o1.w * adv.w;
        #pragma unroll
        for (int off = 8; off > 0; off >>= 1) {
            ps += __shfl_down(ps, off);
            pd += __shfl_down(pd, off);
        }
        if (((lane & 15) == 0) && ok) {
            alS[gr * 4 + cs] = ps;
            alD[gr * 4 + cs] = pd;
        }
    }
}

// ---------------- CSR softmax-aggregation, inline edge weights, 8-deep gather pipeline ----------------
// w = exp(lrelu(alS[src]+alD[node])) computed in-loop (broadcast load + 2 VALU, hidden
// under the 1KB row-gather latency). No max-subtraction: logits are O(1).

template <int H>
__global__ __launch_bounds__(256) void k_agg(const float* __restrict__ h, const float* __restrict__ alS,
                                             const float* __restrict__ alD, const int* __restrict__ offs,
                                             const int* __restrict__ csr_src, const float* __restrict__ bias,
                                             float* __restrict__ out) {
    int node = blockIdx.x * 4 + (threadIdx.x >> 6);
    int lane = threadIdx.x & 63;
    if (node >= N_NODES) return;
    const int head = (H == 4) ? (lane >> 4) : 0;
    const float ald = alD[node * H + head];
    int e0 = offs[node], e1 = offs[node + 1];
    const float* hp = h + lane * 4;
    float den = 0.f, a0 = 0.f, a1 = 0.f, a2 = 0.f, a3 = 0.f;
    int e = e0;
    for (; e + 8 <= e1; e += 8) {
        int s[8];
        #pragma unroll
        for (int i = 0; i < 8; i++) s[i] = csr_src[e + i];
        float4 hv[8];
        #pragma unroll
        for (int i = 0; i < 8; i++) hv[i] = *(const float4*)(hp + s[i] * 256);
        float w[8];
        #pragma unroll
        for (int i = 0; i < 8; i++) {
            float v = alS[s[i] * H + head] + ald;
            v = (v > 0.f) ? v : 0.2f * v;
            w[i] = __expf(v);
        }
        #pragma unroll
        for (int i = 0; i < 8; i++) {
            den += w[i];
            a0 += w[i] * hv[i].x; a1 += w[i] * hv[i].y;
            a2 += w[i] * hv[i].z; a3 += w[i] * hv[i].w;
        }
    }
    for (; e < e1; e++) {
        int s = csr_src[e];
        float v = alS[s * H + head] + ald;
        v = (v > 0.f) ? v : 0.2f * v;
        float w = __expf(v);
        const float4 hv = *(const float4*)(hp + s * 256);
        den += w;
        a0 += w * hv.x; a1 += w * hv.y; a2 += w * hv.z; a3 += w * hv.w;
    }
    float inv = 1.f / den;
    const float4 bv = *(const float4*)(bias + lane * 4);
    float4 o = {a0 * inv + bv.x, a1 * inv + bv.y, a2 * inv + bv.z, a3 * inv + bv.w};
    *(float4*)(out + node * 256 + lane * 4) = o;
}

// ---------------- BatchNorm stats ----------------

__global__ __launch_bounds__(256) void k_bnstats(const float* __restrict__ x, float* __restrict__ sum,
                                                 float* __restrict__ sumsq) {
    int c = threadIdx.x;
    float s = 0.f, q = 0.f;
    for (int r = blockIdx.x; r < N_NODES; r += gridDim.x) {
        float v = x[r * 256 + c];
        s += v; q += v * v;
    }
    atomicAdd(&sum[c], s);
    atomicAdd(&sumsq[c], q);
}

// consumes sum/sumsq and re-zeroes them for the next bnstats (saves 3 memsets/launch)
__global__ __launch_bounds__(256) void k_bnfin(float* __restrict__ sum, float* __restrict__ sumsq,
                                               const float* __restrict__ g, const float* __restrict__ be,
                                               float* __restrict__ scale, float* __restrict__ shift) {
    int c = threadIdx.x;
    float mu = sum[c] * (1.f / N_NODES);
    float var = sumsq[c] * (1.f / N_NODES) - mu * mu;
    float sc = g[c] * rsqrtf(var + 1e-5f);
    scale[c] = sc;
    shift[c] = be[c] - mu * sc;
    sum[c] = 0.f;
    sumsq[c] = 0.f;
}

// ---------------- GEMM relu(bn(A))@B [N,256]x[256,256], 64x64 tiles, alpha partials fused ----------------

__global__ __launch_bounds__(256) void k_gemm256(const float* __restrict__ A, const float* __restrict__ scale,
                                                 const float* __restrict__ shift, const float* __restrict__ B,
                                                 const float* __restrict__ a_s, const float* __restrict__ a_d,
                                                 float* __restrict__ C, float* __restrict__ alSp,
                                                 float* __restrict__ alDp) {
    const int rb = blockIdx.x >> 2, cs = blockIdx.x & 3;
    const int row0 = rb * 64;
    const int col0 = cs * 64;
    const int nrows = min(64, N_NODES - row0);
    const int t = threadIdx.x;
    __shared__ float xs[32 * 68];  // A^T [k][r], stride 68
    __shared__ float bs[32 * 64];  // [k][c]
    __shared__ float scs[256], shs[256];
    scs[t] = scale[t];
    shs[t] = shift[t];
    const int lane = t & 63;
    const int rl = (t & 15) | ((t >> 6) << 4);  // 0..63, row from low lane bits (2-way write banks)
    const int c4 = (t >> 4) & 3;
    const int c0 = (t & 15) * 4;
    const int r0 = (t >> 4) * 4;
    float acc[4][4] = {};
    for (int k0 = 0; k0 < 256; k0 += 32) {
        __syncthreads();  // first iter also covers scs/shs
        {
            #pragma unroll
            for (int jj = 0; jj < 2; jj++) {
                int cc = c4 + 4 * jj;  // float4-col 0..7
                int kcol = k0 + cc * 4;
                float4 w = {0.f, 0.f, 0.f, 0.f};
                if (rl < nrows) {
                    float4 v = *(const float4*)(A + (row0 + rl) * 256 + kcol);
                    w.x = fmaxf(v.x * scs[kcol + 0] + shs[kcol + 0], 0.f);
                    w.y = fmaxf(v.y * scs[kcol + 1] + shs[kcol + 1], 0.f);
                    w.z = fmaxf(v.z * scs[kcol + 2] + shs[kcol + 2], 0.f);
                    w.w = fmaxf(v.w * scs[kcol + 3] + shs[kcol + 3], 0.f);
                }
                xs[(cc * 4 + 0) * 68 + rl] = w.x;
                xs[(cc * 4 + 1) * 68 + rl] = w.y;
                xs[(cc * 4 + 2) * 68 + rl] = w.z;
                xs[(cc * 4 + 3) * 68 + rl] = w.w;
            }
        }
        {
            int ccB = (t & 15) * 4;
            int kB = t >> 4;
            #pragma unroll
            for (int pass = 0; pass < 2; pass++, kB += 16) {
                *(float4*)(bs + kB * 64 + ccB) = *(const float4*)(B + (k0 + kB) * 256 + col0 + ccB);
            }
        }
        __syncthreads();
        #pragma unroll 8
        for (int k = 0; k < 32; k++) {
            float4 av = *(const float4*)(xs + k * 68 + r0);
            float4 bv = *(const float4*)(bs + k * 64 + c0);
            float a[4] = {av.x, av.y, av.z, av.w};
            #pragma unroll
            for (int i = 0; i < 4; i++) {
                acc[i][0] += a[i] * bv.x; acc[i][1] += a[i] * bv.y;
                acc[i][2] += a[i] * bv.z; acc[i][3] += a[i] * bv.w;
            }
        }
    }
    // epilogue: write C + per-strip alpha partials (H=1)
    float4 asv = *(const float4*)(a_s + col0 + c0);
    float4 adv = *(const float4*)(a_d + col0 + c0);
    #pragma unroll
    for (int i = 0; i < 4; i++) {
        int gr = row0 + r0 + i;
        bool ok = (r0 + i) < nrows;
        float4 o = {acc[i][0], acc[i][1], acc[i][2], acc[i][3]};
        if (ok) *(float4*)(C + gr * 256 + col0 + c0) = o;
        float ps = o.x * asv.x + o.y * asv.y + o.z * asv.z + o.w * asv.w;
        float pd = o.x * adv.x + o.y * adv.y + o.z * adv.z + o.w * adv.w;
        #pragma unroll
        for (int off = 8; off > 0; off >>= 1) {
            ps += __shfl_down(ps, off);
            pd += __shfl_down(pd, off);
        }
        if (((lane & 15) == 0) && ok) {
            alSp[cs * N_NODES + gr] = ps;
            alDp[cs * N_NODES + gr] = pd;
        }
    }
}

__global__ __launch_bounds__(256) void k_alred(const float* __restrict__ alSp, const float* __restrict__ alDp,
                                               float* __restrict__ alS, float* __restrict__ alD) {
    int n = blockIdx.x * 256 + threadIdx.x;
    if (n >= N_NODES) return;
    alS[n] = (alSp[n] + alSp[N_NODES + n]) + (alSp[2 * N_NODES + n] + alSp[3 * N_NODES + n]);
    alD[n] = (alDp[n] + alDp[N_NODES + n]) + (alDp[2 * N_NODES + n] + alDp[3 * N_NODES + n]);
}

// ---------------- final GEMM ((relu(bn(A))+res)*invsqrt2)@Wf+bf -> [N,64], 32x64 tiles ----------------

__global__ __launch_bounds__(256) void k_gemm_final(const float* __restrict__ A, const float* __restrict__ scale,
                                                    const float* __restrict__ shift, const float* __restrict__ res,
                                                    const float* __restrict__ B, const float* __restrict__ bias,
                                                    float* __restrict__ y) {
    const int row0 = blockIdx.x * 32;  // 625 blocks, exact
    const int t = threadIdx.x;
    const float INVS = 0.70710678118654752440f;
    __shared__ float xs[32 * 36];  // A^T [k][r], stride 36
    __shared__ float bs[32 * 64];  // [k][c]
    __shared__ float scs[256], shs[256];
    scs[t] = scale[t];
    shs[t] = shift[t];
    const int rf = (t & 15) | ((t >> 7) << 4);  // 0..31
    const int cf = (t >> 4) & 7;                // float4-col 0..7
    const int c0 = (t & 15) * 4;
    const int r0 = (t >> 4) * 2;
    float acc[2][4] = {};
    for (int k0 = 0; k0 < 256; k0 += 32) {
        __syncthreads();
        {
            int kcol = k0 + cf * 4;
            int gi = (row0 + rf) * 256 + kcol;
            float4 v = *(const float4*)(A + gi);
            float4 rv = *(const float4*)(res + gi);
            xs[(cf * 4 + 0) * 36 + rf] = (fmaxf(v.x * scs[kcol + 0] + shs[kcol + 0], 0.f) + rv.x) * INVS;
            xs[(cf * 4 + 1) * 36 + rf] = (fmaxf(v.y * scs[kcol + 1] + shs[kcol + 1], 0.f) + rv.y) * INVS;
            xs[(cf * 4 + 2) * 36 + rf] = (fmaxf(v.z * scs[kcol + 2] + shs[kcol + 2], 0.f) + rv.z) * INVS;
            xs[(cf * 4 + 3) * 36 + rf] = (fmaxf(v.w * scs[kcol + 3] + shs[kcol + 3], 0.f) + rv.w) * INVS;
        }
        {
            int cc = (t & 15) * 4;
            int k = t >> 4;
            #pragma unroll
            for (int pass = 0; pass < 2; pass++, k += 16) {
                *(float4*)(bs + k * 64 + cc) = *(const float4*)(B + (k0 + k) * 64 + cc);
            }
        }
        __syncthreads();
        #pragma unroll 8
        for (int k = 0; k < 32; k++) {
            float2 av = *(const float2*)(xs + k * 36 + r0);
            float4 bv = *(const float4*)(bs + k * 64 + c0);
            acc[0][0] += av.x * bv.x; acc[0][1] += av.x * bv.y;
            acc[0][2] += av.x * bv.z; acc[0][3] += av.x * bv.w;
            acc[1][0] += av.y * bv.x; acc[1][1] += av.y * bv.y;
            acc[1][2] += av.y * bv.z; acc[1][3] += av.y * bv.w;
        }
    }
    float4 bv = *(const float4*)(bias + c0);
    #pragma unroll
    for (int i = 0; i < 2; i++) {
        int gr = row0 + r0 + i;
        float4 o = {acc[i][0] + bv.x, acc[i][1] + bv.y, acc[i][2] + bv.z, acc[i][3] + bv.w};
        *(float4*)(y + gr * 64 + c0) = o;
    }
}

// ---------------- fused mean-pool (sorted batch) + MLP head ----------------

__global__ __launch_bounds__(256) void k_pool_head(const float* __restrict__ x, const int* __restrict__ batch,
                                                   const float* __restrict__ Wh1, const float* __restrict__ bh1,
                                                   const float* __restrict__ Wh2, const float* __restrict__ bh2,
                                                   float* __restrict__ out) {
    const int g = blockIdx.x;
    const int t = threadIdx.x;
    int lo = 0, hi = N_NODES;
    while (lo < hi) { int mid = (lo + hi) >> 1; if (batch[mid] < g) lo = mid + 1; else hi = mid; }
    int start = lo;
    hi = N_NODES;
    while (lo < hi) { int mid = (lo + hi) >> 1; if (batch[mid] < g + 1) lo = mid + 1; else hi = mid; }
    int end = lo;
    float cnt = (float)(end - start);

    __shared__ float part[256];
    __shared__ float p[64];
    __shared__ float hrow[256];
    const int c = t & 63;
    float s = 0.f;
    for (int r = start + (t >> 6); r < end; r += 4) s += x[r * 64 + c];
    part[t] = s;
    __syncthreads();
    if (t < 64) {
        float v = part[t] + part[t + 64] + part[t + 128] + part[t + 192];
        p[t] = v / fmaxf(cnt, 1.f);
    }
    __syncthreads();
    float a = bh1[t];
    #pragma unroll 8
    for (int k = 0; k < 64; k++) a += p[k] * Wh1[k * 256 + t];
    hrow[t] = fmaxf(a, 0.f);
    __syncthreads();
    if (t < 128) {
        float o = bh2[t];
        #pragma unroll 8
        for (int k = 0; k < 256; k++) o += hrow[k] * Wh2[k * 128 + t];
        out[g * 128 + t] = o;
    }
}

// ---------------- host ----------------

extern "C" void kernel_launch(void* const* d_in, const int* in_sizes, int n_in,
                              void* d_out, int out_size, void* d_ws, size_t ws_size,
                              hipStream_t stream) {
    (void)in_sizes; (void)n_in; (void)out_size; (void)ws_size;
    const float* x0 = (const float*)d_in[0];
    const int* ei = (const int*)d_in[1];
    const int* batch = (const int*)d_in[2];
    const float* Wh1 = (const float*)d_in[35];
    const float* bh1 = (const float*)d_in[36];
    const float* Wh2 = (const float*)d_in[37];
    const float* bh2 = (const float*)d_in[38];

    char* p = (char*)d_ws;
    auto alloc = [&](size_t bytes) -> void* {
        void* r = (void*)p;
        p += (bytes + 255) & ~(size_t)255;
        return r;
    };
    // counts + bnsum adjacent -> single zeroing memset
    int* counts = (int*)alloc((size_t)N_NODES * 4);     // 80000 -> 80128 padded
    float* bnsum = (float*)alloc(2048);                 // sum[256] + sumsq[256]
    float* bnsq = bnsum + 256;
    const size_t zero_bytes = (((size_t)N_NODES * 4 + 255) & ~(size_t)255) + 2048;
    int* offs = (int*)alloc((size_t)(N_NODES + 1) * 4);
    int* cursor = (int*)alloc((size_t)N_NODES * 4);
    int* csr_src = (int*)alloc((size_t)ETOT * 4);
    float* alS = (float*)alloc((size_t)N_NODES * 4 * 4);  // H=4 (also reused as H=1)
    float* alD = (float*)alloc((size_t)N_NODES * 4 * 4);
    float* alSp = (float*)alloc((size_t)N_NODES * 4 * 4);  // per-strip partials
    float* alDp = (float*)alloc((size_t)N_NODES * 4 * 4);
    float* scaleb = (float*)alloc(1024);
    float* shiftb = (float*)alloc(1024);
    float* hbuf = (float*)alloc((size_t)N_NODES * 256 * 4);
    float* obuf = (float*)alloc((size_t)N_NODES * 256 * 4);
    float* rbuf = (float*)alloc((size_t)N_NODES * 256 * 4);
    float* xout = (float*)alloc((size_t)N_NODES * 64 * 4);

    // --- CSR by dst ---
    hipMemsetAsync(counts, 0, zero_bytes, stream);  // counts + bnsum/bnsq
    k_hist<<<(ETOT + 255) / 256, 256, 0, stream>>>(ei, counts);
    k_scan<<<1, 1024, 0, stream>>>(counts, offs, cursor);
    k_scatter<<<(ETOT + 255) / 256, 256, 0, stream>>>(ei, cursor, csr_src);

    const int tile64_blocks = ((N_NODES + 63) / 64) * 4;  // 313*4 = 1252
    const int node_blocks = (N_NODES + 3) / 4;            // 5000
    const int red_blocks = (N_NODES + 255) / 256;
    const int final_blocks = N_NODES / 32;                // 625

    auto run_block = [&](const float* xin, int base) {
        const float* W1 = (const float*)d_in[base + 0];
        const float* a1s = (const float*)d_in[base + 1];
        const float* a1d = (const float*)d_in[base + 2];
        const float* b1 = (const float*)d_in[base + 3];
        const float* g1 = (const float*)d_in[base + 4];
        const float* be1 = (const float*)d_in[base + 5];
        const float* W2 = (const float*)d_in[base + 6];
        const float* a2s = (const float*)d_in[base + 7];
        const float* a2d = (const float*)d_in[base + 8];
        const float* b2 = (const float*)d_in[base + 9];
        const float* g2 = (const float*)d_in[base + 10];
        const float* be2 = (const float*)d_in[base + 11];
        const float* Wr = (const float*)d_in[base + 12];
        const float* br = (const float*)d_in[base + 13];
        const float* Wf = (const float*)d_in[base + 14];
        const float* bf = (const float*)d_in[base + 15];

        // h1 = x@W1 ; res = x@Wr + br ; alpha1 fused (strip == head)
        k_gemm64_dual<<<tile64_blocks, 256, 0, stream>>>(xin, W1, Wr, br, a1s, a1d, hbuf, rbuf, alS, alD);
        // GAT1 (H=4), inline edge weights
        k_agg<4><<<node_blocks, 256, 0, stream>>>(hbuf, alS, alD, offs, csr_src, b1, obuf);
        // BN1 (bnsum/bnsq pre-zeroed; k_bnfin re-zeroes)
        k_bnstats<<<256, 256, 0, stream>>>(obuf, bnsum, bnsq);
        k_bnfin<<<1, 256, 0, stream>>>(bnsum, bnsq, g1, be1, scaleb, shiftb);
        // h2 = relu(bn(out1)) @ W2 ; alpha2 partials fused
        k_gemm256<<<tile64_blocks, 256, 0, stream>>>(obuf, scaleb, shiftb, W2, a2s, a2d, hbuf, alSp, alDp);
        k_alred<<<red_blocks, 256, 0, stream>>>(alSp, alDp, alS, alD);
        // GAT2 (H=1), inline edge weights
        k_agg<1><<<node_blocks, 256, 0, stream>>>(hbuf, alS, alD, offs, csr_src, b2, obuf);
        // BN2
        k_bnstats<<<256, 256, 0, stream>>>(obuf, bnsum, bnsq);
        k_bnfin<<<1, 256, 0, stream>>>(bnsum, bnsq, g2, be2, scaleb, shiftb);
        // y = ((relu(bn(out2)) + res) * invsqrt2) @ Wf + bf
        k_gemm_final<<<final_blocks, 256, 0, stream>>>(obuf, scaleb, shiftb, rbuf, Wf, bf, xout);
    };

    run_block(x0, 3);
    run_block(xout, 19);

    // --- fused mean-pool + head ---
    k_pool_head<<<G_GROUPS, 256, 0, stream>>>(xout, batch, Wh1, bh1, Wh2, bh2, (float*)d_out);
}

// Round 9
// 675.150 us; speedup vs baseline: 1.0941x; 1.0452x over previous
//
#include <hip/hip_runtime.h>

#define N_NODES 20000
#define N_EDGES 320000
#define ETOT (N_EDGES + N_NODES)
#define G_GROUPS 64

// bf16 helpers (RNE)
__device__ __forceinline__ unsigned short f2bf(float f) {
    unsigned int u = __float_as_uint(f);
    u += 0x7fffu + ((u >> 16) & 1u);
    return (unsigned short)(u >> 16);
}
__device__ __forceinline__ float bf2f(unsigned short v) {
    return __uint_as_float(((unsigned int)v) << 16);
}

// ---------------- CSR build ----------------

__global__ __launch_bounds__(256) void k_hist(const int* __restrict__ ei, int* __restrict__ counts) {
    int e = blockIdx.x * 256 + threadIdx.x;
    if (e >= ETOT) return;
    int dst = (e < N_EDGES) ? ei[N_EDGES + e] : (e - N_EDGES);
    atomicAdd(&counts[dst], 1);
}

__global__ __launch_bounds__(1024) void k_scan(const int* __restrict__ counts, int* __restrict__ offs,
                                               int* __restrict__ cursor) {
    __shared__ int sdata[1024];
    const int t = threadIdx.x;
    const int chunk = (N_NODES + 1023) / 1024;  // 20
    int base = t * chunk;
    int s = 0;
    for (int i = 0; i < chunk; i++) { int idx = base + i; if (idx < N_NODES) s += counts[idx]; }
    sdata[t] = s;
    __syncthreads();
    for (int off = 1; off < 1024; off <<= 1) {
        int v = (t >= off) ? sdata[t - off] : 0;
        __syncthreads();
        sdata[t] += v;
        __syncthreads();
    }
    int prefix = (t == 0) ? 0 : sdata[t - 1];
    for (int i = 0; i < chunk; i++) {
        int idx = base + i;
        if (idx < N_NODES) {
            int cv = counts[idx];
            offs[idx] = prefix;
            cursor[idx] = prefix;
            prefix += cv;
        }
    }
    if (t == 1023) offs[N_NODES] = sdata[1023];
}

__global__ __launch_bounds__(256) void k_scatter(const int* __restrict__ ei, int* __restrict__ cursor,
                                                 int* __restrict__ csr_src) {
    int e = blockIdx.x * 256 + threadIdx.x;
    if (e >= ETOT) return;
    int src = (e < N_EDGES) ? ei[e] : (e - N_EDGES);
    int dst = (e < N_EDGES) ? ei[N_EDGES + e] : (e - N_EDGES);
    int p = atomicAdd(&cursor[dst], 1);
    csr_src[p] = src;
}

// ---------------- dual GEMM [N,64]x[64,256], 64x64 tiles, alpha fused (strip==head) ----------------
// h output stored bf16 (only consumer is k_agg); res + logits stay fp32.

__global__ __launch_bounds__(256) void k_gemm64_dual(const float* __restrict__ x, const float* __restrict__ W1,
                                                     const float* __restrict__ Wr, const float* __restrict__ br,
                                                     const float* __restrict__ a_s, const float* __restrict__ a_d,
                                                     unsigned short* __restrict__ hbf, float* __restrict__ res,
                                                     float* __restrict__ alS, float* __restrict__ alD) {
    const int rb = blockIdx.x >> 2, cs = blockIdx.x & 3;
    const int row0 = rb * 64;
    const int nrows = min(64, N_NODES - row0);
    const int t = threadIdx.x;
    __shared__ float xs[32 * 68];   // A^T [k][r], stride 68
    __shared__ float b1s[32 * 64];  // [k][c]
    __shared__ float brs[32 * 64];
    const int lane = t & 63;
    const int c0 = (t & 15) * 4;
    const int r0 = (t >> 4) * 4;
    const int rl = (t & 15) | ((t >> 6) << 4);  // 0..63 (2-way free write banks)
    const int c4 = (t >> 4) & 3;
    float acc1[4][4] = {}, acc2[4][4] = {};
    for (int k0 = 0; k0 < 64; k0 += 32) {
        if (k0) __syncthreads();
        {
            #pragma unroll
            for (int jj = 0; jj < 2; jj++) {
                int cc = c4 + 4 * jj;  // 0..7
                float4 v = {0.f, 0.f, 0.f, 0.f};
                if (rl < nrows) v = *(const float4*)(x + (row0 + rl) * 64 + k0 + cc * 4);
                xs[(cc * 4 + 0) * 68 + rl] = v.x;
                xs[(cc * 4 + 1) * 68 + rl] = v.y;
                xs[(cc * 4 + 2) * 68 + rl] = v.z;
                xs[(cc * 4 + 3) * 68 + rl] = v.w;
            }
        }
        {
            int cc = (t & 15) * 4;
            int k = t >> 4;
            #pragma unroll
            for (int pass = 0; pass < 2; pass++, k += 16) {
                *(float4*)(b1s + k * 64 + cc) = *(const float4*)(W1 + (k0 + k) * 256 + cs * 64 + cc);
                *(float4*)(brs + k * 64 + cc) = *(const float4*)(Wr + (k0 + k) * 256 + cs * 64 + cc);
            }
        }
        __syncthreads();
        #pragma unroll 8
        for (int k = 0; k < 32; k++) {
            float4 av = *(const float4*)(xs + k * 68 + r0);
            float4 b1 = *(const float4*)(b1s + k * 64 + c0);
            float4 b2 = *(const float4*)(brs + k * 64 + c0);
            float a[4] = {av.x, av.y, av.z, av.w};
            #pragma unroll
            for (int i = 0; i < 4; i++) {
                acc1[i][0] += a[i] * b1.x; acc1[i][1] += a[i] * b1.y;
                acc1[i][2] += a[i] * b1.z; acc1[i][3] += a[i] * b1.w;
                acc2[i][0] += a[i] * b2.x; acc2[i][1] += a[i] * b2.y;
                acc2[i][2] += a[i] * b2.z; acc2[i][3] += a[i] * b2.w;
            }
        }
    }
    const int gcol = cs * 64 + c0;
    float4 bv = *(const float4*)(br + gcol);
    float4 asv = *(const float4*)(a_s + gcol);
    float4 adv = *(const float4*)(a_d + gcol);
    #pragma unroll
    for (int i = 0; i < 4; i++) {
        int gr = row0 + r0 + i;
        bool ok = (r0 + i) < nrows;
        float4 o1 = {acc1[i][0], acc1[i][1], acc1[i][2], acc1[i][3]};
        if (ok) {
            ushort4 hq = {f2bf(o1.x), f2bf(o1.y), f2bf(o1.z), f2bf(o1.w)};
            *(ushort4*)(hbf + gr * 256 + gcol) = hq;
            float4 o2 = {acc2[i][0] + bv.x, acc2[i][1] + bv.y, acc2[i][2] + bv.z, acc2[i][3] + bv.w};
            *(float4*)(res + gr * 256 + gcol) = o2;
        }
        float ps = o1.x * asv.x + o1.y * asv.y + o1.z * asv.z + o1.w * asv.w;
        float pd = o1.x * adv.x + o1.y * adv.y + o1.z * adv.z + o1.w * adv.w;
        #pragma unroll
        for (int off = 8; off > 0; off >>= 1) {
            ps += __shfl_down(ps, off);
            pd += __shfl_down(pd, off);
        }
        if (((lane & 15) == 0) && ok) {
            alS[gr * 4 + cs] = ps;
            alD[gr * 4 + cs] = pd;
        }
    }
}

// ---------------- CSR softmax-aggregation on bf16 h, inline fp32 edge weights ----------------

template <int H>
__global__ __launch_bounds__(256) void k_agg(const unsigned short* __restrict__ hbf, const float* __restrict__ alS,
                                             const float* __restrict__ alD, const int* __restrict__ offs,
                                             const int* __restrict__ csr_src, const float* __restrict__ bias,
                                             float* __restrict__ out) {
    int node = blockIdx.x * 4 + (threadIdx.x >> 6);
    int lane = threadIdx.x & 63;
    if (node >= N_NODES) return;
    const int head = (H == 4) ? (lane >> 4) : 0;
    const float ald = alD[node * H + head];
    int e0 = offs[node], e1 = offs[node + 1];
    const unsigned short* hp = hbf + lane * 4;
    float den = 0.f, a0 = 0.f, a1 = 0.f, a2 = 0.f, a3 = 0.f;
    int e = e0;
    for (; e + 8 <= e1; e += 8) {
        int s[8];
        #pragma unroll
        for (int i = 0; i < 8; i++) s[i] = csr_src[e + i];
        ushort4 hq[8];
        #pragma unroll
        for (int i = 0; i < 8; i++) hq[i] = *(const ushort4*)(hp + s[i] * 256);
        float w[8];
        #pragma unroll
        for (int i = 0; i < 8; i++) {
            float v = alS[s[i] * H + head] + ald;
            v = (v > 0.f) ? v : 0.2f * v;
            w[i] = __expf(v);
        }
        #pragma unroll
        for (int i = 0; i < 8; i++) {
            den += w[i];
            a0 += w[i] * bf2f(hq[i].x); a1 += w[i] * bf2f(hq[i].y);
            a2 += w[i] * bf2f(hq[i].z); a3 += w[i] * bf2f(hq[i].w);
        }
    }
    for (; e < e1; e++) {
        int s = csr_src[e];
        float v = alS[s * H + head] + ald;
        v = (v > 0.f) ? v : 0.2f * v;
        float w = __expf(v);
        ushort4 hq = *(const ushort4*)(hp + s * 256);
        den += w;
        a0 += w * bf2f(hq.x); a1 += w * bf2f(hq.y); a2 += w * bf2f(hq.z); a3 += w * bf2f(hq.w);
    }
    float inv = 1.f / den;
    const float4 bv = *(const float4*)(bias + lane * 4);
    float4 o = {a0 * inv + bv.x, a1 * inv + bv.y, a2 * inv + bv.z, a3 * inv + bv.w};
    *(float4*)(out + node * 256 + lane * 4) = o;
}

// ---------------- BatchNorm: stats + finalize fused (last-block-done) ----------------

__global__ __launch_bounds__(256) void k_bnstats_fin(const float* __restrict__ x, float* __restrict__ sum,
                                                     float* __restrict__ sumsq, const float* __restrict__ g,
                                                     const float* __restrict__ be, float* __restrict__ scale,
                                                     float* __restrict__ shift, int* __restrict__ counter) {
    const int c = threadIdx.x;
    float s = 0.f, q = 0.f;
    for (int r = blockIdx.x; r < N_NODES; r += gridDim.x) {
        float v = x[r * 256 + c];
        s += v; q += v * v;
    }
    atomicAdd(&sum[c], s);
    atomicAdd(&sumsq[c], q);
    __threadfence();
    __syncthreads();
    __shared__ int lastFlag;
    if (c == 0) lastFlag = (atomicAdd(counter, 1) == (int)gridDim.x - 1);
    __syncthreads();
    if (lastFlag) {
        float S = atomicAdd(&sum[c], 0.f);    // coherent read
        float Q = atomicAdd(&sumsq[c], 0.f);
        float mu = S * (1.f / N_NODES);
        float var = Q * (1.f / N_NODES) - mu * mu;
        float sc = g[c] * rsqrtf(var + 1e-5f);
        scale[c] = sc;
        shift[c] = be[c] - mu * sc;
        sum[c] = 0.f;    // re-zero for next BN (visible at kernel boundary)
        sumsq[c] = 0.f;
        if (c == 0) *counter = 0;
    }
}

// ---------------- GEMM relu(bn(A))@B [N,256]x[256,256], 64x64 tiles, alpha partials fused ----------------
// C output stored bf16 (only consumer is k_agg<1>); alpha partials fp32 from accumulators.

__global__ __launch_bounds__(256) void k_gemm256(const float* __restrict__ A, const float* __restrict__ scale,
                                                 const float* __restrict__ shift, const float* __restrict__ B,
                                                 const float* __restrict__ a_s, const float* __restrict__ a_d,
                                                 unsigned short* __restrict__ C, float* __restrict__ alSp,
                                                 float* __restrict__ alDp) {
    const int rb = blockIdx.x >> 2, cs = blockIdx.x & 3;
    const int row0 = rb * 64;
    const int col0 = cs * 64;
    const int nrows = min(64, N_NODES - row0);
    const int t = threadIdx.x;
    __shared__ float xs[32 * 68];  // A^T [k][r], stride 68
    __shared__ float bs[32 * 64];  // [k][c]
    __shared__ float scs[256], shs[256];
    scs[t] = scale[t];
    shs[t] = shift[t];
    const int lane = t & 63;
    const int rl = (t & 15) | ((t >> 6) << 4);
    const int c4 = (t >> 4) & 3;
    const int c0 = (t & 15) * 4;
    const int r0 = (t >> 4) * 4;
    float acc[4][4] = {};
    for (int k0 = 0; k0 < 256; k0 += 32) {
        __syncthreads();  // first iter also covers scs/shs
        {
            #pragma unroll
            for (int jj = 0; jj < 2; jj++) {
                int cc = c4 + 4 * jj;
                int kcol = k0 + cc * 4;
                float4 w = {0.f, 0.f, 0.f, 0.f};
                if (rl < nrows) {
                    float4 v = *(const float4*)(A + (row0 + rl) * 256 + kcol);
                    w.x = fmaxf(v.x * scs[kcol + 0] + shs[kcol + 0], 0.f);
                    w.y = fmaxf(v.y * scs[kcol + 1] + shs[kcol + 1], 0.f);
                    w.z = fmaxf(v.z * scs[kcol + 2] + shs[kcol + 2], 0.f);
                    w.w = fmaxf(v.w * scs[kcol + 3] + shs[kcol + 3], 0.f);
                }
                xs[(cc * 4 + 0) * 68 + rl] = w.x;
                xs[(cc * 4 + 1) * 68 + rl] = w.y;
                xs[(cc * 4 + 2) * 68 + rl] = w.z;
                xs[(cc * 4 + 3) * 68 + rl] = w.w;
            }
        }
        {
            int ccB = (t & 15) * 4;
            int kB = t >> 4;
            #pragma unroll
            for (int pass = 0; pass < 2; pass++, kB += 16) {
                *(float4*)(bs + kB * 64 + ccB) = *(const float4*)(B + (k0 + kB) * 256 + col0 + ccB);
            }
        }
        __syncthreads();
        #pragma unroll 8
        for (int k = 0; k < 32; k++) {
            float4 av = *(const float4*)(xs + k * 68 + r0);
            float4 bv = *(const float4*)(bs + k * 64 + c0);
            float a[4] = {av.x, av.y, av.z, av.w};
            #pragma unroll
            for (int i = 0; i < 4; i++) {
                acc[i][0] += a[i] * bv.x; acc[i][1] += a[i] * bv.y;
                acc[i][2] += a[i] * bv.z; acc[i][3] += a[i] * bv.w;
            }
        }
    }
    float4 asv = *(const float4*)(a_s + col0 + c0);
    float4 adv = *(const float4*)(a_d + col0 + c0);
    #pragma unroll
    for (int i = 0; i < 4; i++) {
        int gr = row0 + r0 + i;
        bool ok = (r0 + i) < nrows;
        float4 o = {acc[i][0], acc[i][1], acc[i][2], acc[i][3]};
        if (ok) {
            ushort4 hq = {f2bf(o.x), f2bf(o.y), f2bf(o.z), f2bf(o.w)};
            *(ushort4*)(C + gr * 256 + col0 + c0) = hq;
        }
        float ps = o.x * asv.x + o.y * asv.y + o.z * asv.z + o.w * asv.w;
        float pd = o.x * adv.x + o.y * adv.y + o.z * adv.z + o.w * adv.w;
        #pragma unroll
        for (int off = 8; off > 0; off >>= 1) {
            ps += __shfl_down(ps, off);
            pd += __shfl_down(pd, off);
        }
        if (((lane & 15) == 0) && ok) {
            alSp[cs * N_NODES + gr] = ps;
            alDp[cs * N_NODES + gr] = pd;
        }
    }
}

__global__ __launch_bounds__(256) void k_alred(const float* __restrict__ alSp, const float* __restrict__ alDp,
                                               float* __restrict__ alS, float* __restrict__ alD) {
    int n = blockIdx.x * 256 + threadIdx.x;
    if (n >= N_NODES) return;
    alS[n] = (alSp[n] + alSp[N_NODES + n]) + (alSp[2 * N_NODES + n] + alSp[3 * N_NODES + n]);
    alD[n] = (alDp[n] + alDp[N_NODES + n]) + (alDp[2 * N_NODES + n] + alDp[3 * N_NODES + n]);
}

// ---------------- final GEMM ((relu(bn(A))+res)*invsqrt2)@Wf+bf -> [N,64], 32x64 tiles ----------------

__global__ __launch_bounds__(256) void k_gemm_final(const float* __restrict__ A, const float* __restrict__ scale,
                                                    const float* __restrict__ shift, const float* __restrict__ res,
                                                    const float* __restrict__ B, const float* __restrict__ bias,
                                                    float* __restrict__ y) {
    const int row0 = blockIdx.x * 32;  // 625 blocks, exact
    const int t = threadIdx.x;
    const float INVS = 0.70710678118654752440f;
    __shared__ float xs[32 * 36];
    __shared__ float bs[32 * 64];
    __shared__ float scs[256], shs[256];
    scs[t] = scale[t];
    shs[t] = shift[t];
    const int rf = (t & 15) | ((t >> 7) << 4);  // 0..31
    const int cf = (t >> 4) & 7;
    const int c0 = (t & 15) * 4;
    const int r0 = (t >> 4) * 2;
    float acc[2][4] = {};
    for (int k0 = 0; k0 < 256; k0 += 32) {
        __syncthreads();
        {
            int kcol = k0 + cf * 4;
            int gi = (row0 + rf) * 256 + kcol;
            float4 v = *(const float4*)(A + gi);
            float4 rv = *(const float4*)(res + gi);
            xs[(cf * 4 + 0) * 36 + rf] = (fmaxf(v.x * scs[kcol + 0] + shs[kcol + 0], 0.f) + rv.x) * INVS;
            xs[(cf * 4 + 1) * 36 + rf] = (fmaxf(v.y * scs[kcol + 1] + shs[kcol + 1], 0.f) + rv.y) * INVS;
            xs[(cf * 4 + 2) * 36 + rf] = (fmaxf(v.z * scs[kcol + 2] + shs[kcol + 2], 0.f) + rv.z) * INVS;
            xs[(cf * 4 + 3) * 36 + rf] = (fmaxf(v.w * scs[kcol + 3] + shs[kcol + 3], 0.f) + rv.w) * INVS;
        }
        {
            int cc = (t & 15) * 4;
            int k = t >> 4;
            #pragma unroll
            for (int pass = 0; pass < 2; pass++, k += 16) {
                *(float4*)(bs + k * 64 + cc) = *(const float4*)(B + (k0 + k) * 64 + cc);
            }
        }
        __syncthreads();
        #pragma unroll 8
        for (int k = 0; k < 32; k++) {
            float2 av = *(const float2*)(xs + k * 36 + r0);
            float4 bv = *(const float4*)(bs + k * 64 + c0);
            acc[0][0] += av.x * bv.x; acc[0][1] += av.x * bv.y;
            acc[0][2] += av.x * bv.z; acc[0][3] += av.x * bv.w;
            acc[1][0] += av.y * bv.x; acc[1][1] += av.y * bv.y;
            acc[1][2] += av.y * bv.z; acc[1][3] += av.y * bv.w;
        }
    }
    float4 bv = *(const float4*)(bias + c0);
    #pragma unroll
    for (int i = 0; i < 2; i++) {
        int gr = row0 + r0 + i;
        float4 o = {acc[i][0] + bv.x, acc[i][1] + bv.y, acc[i][2] + bv.z, acc[i][3] + bv.w};
        *(float4*)(y + gr * 64 + c0) = o;
    }
}

// ---------------- fused mean-pool (sorted batch) + MLP head ----------------

__global__ __launch_bounds__(256) void k_pool_head(const float* __restrict__ x, const int* __restrict__ batch,
                                                   const float* __restrict__ Wh1, const float* __restrict__ bh1,
                                                   const float* __restrict__ Wh2, const float* __restrict__ bh2,
                                                   float* __restrict__ out) {
    const int g = blockIdx.x;
    const int t = threadIdx.x;
    int lo = 0, hi = N_NODES;
    while (lo < hi) { int mid = (lo + hi) >> 1; if (batch[mid] < g) lo = mid + 1; else hi = mid; }
    int start = lo;
    hi = N_NODES;
    while (lo < hi) { int mid = (lo + hi) >> 1; if (batch[mid] < g + 1) lo = mid + 1; else hi = mid; }
    int end = lo;
    float cnt = (float)(end - start);

    __shared__ float part[256];
    __shared__ float p[64];
    __shared__ float hrow[256];
    const int c = t & 63;
    float s = 0.f;
    for (int r = start + (t >> 6); r < end; r += 4) s += x[r * 64 + c];
    part[t] = s;
    __syncthreads();
    if (t < 64) {
        float v = part[t] + part[t + 64] + part[t + 128] + part[t + 192];
        p[t] = v / fmaxf(cnt, 1.f);
    }
    __syncthreads();
    float a = bh1[t];
    #pragma unroll 8
    for (int k = 0; k < 64; k++) a += p[k] * Wh1[k * 256 + t];
    hrow[t] = fmaxf(a, 0.f);
    __syncthreads();
    if (t < 128) {
        float o = bh2[t];
        #pragma unroll 8
        for (int k = 0; k < 256; k++) o += hrow[k] * Wh2[k * 128 + t];
        out[g * 128 + t] = o;
    }
}

// ---------------- host ----------------

extern "C" void kernel_launch(void* const* d_in, const int* in_sizes, int n_in,
                              void* d_out, int out_size, void* d_ws, size_t ws_size,
                              hipStream_t stream) {
    (void)in_sizes; (void)n_in; (void)out_size; (void)ws_size;
    const float* x0 = (const float*)d_in[0];
    const int* ei = (const int*)d_in[1];
    const int* batch = (const int*)d_in[2];
    const float* Wh1 = (const float*)d_in[35];
    const float* bh1 = (const float*)d_in[36];
    const float* Wh2 = (const float*)d_in[37];
    const float* bh2 = (const float*)d_in[38];

    char* p = (char*)d_ws;
    auto alloc = [&](size_t bytes) -> void* {
        void* r = (void*)p;
        p += (bytes + 255) & ~(size_t)255;
        return r;
    };
    // zeroed region: counts + bnsum/bnsq + bn counter (single memset)
    int* counts = (int*)alloc((size_t)N_NODES * 4);  // padded to 80128
    float* bnsum = (float*)alloc(2048);              // sum[256] + sumsq[256]
    float* bnsq = bnsum + 256;
    int* bncnt = (int*)alloc(256);
    const size_t zero_bytes = (((size_t)N_NODES * 4 + 255) & ~(size_t)255) + 2048 + 256;
    int* offs = (int*)alloc((size_t)(N_NODES + 1) * 4);
    int* cursor = (int*)alloc((size_t)N_NODES * 4);
    int* csr_src = (int*)alloc((size_t)ETOT * 4);
    float* alS = (float*)alloc((size_t)N_NODES * 4 * 4);
    float* alD = (float*)alloc((size_t)N_NODES * 4 * 4);
    float* alSp = (float*)alloc((size_t)N_NODES * 4 * 4);
    float* alDp = (float*)alloc((size_t)N_NODES * 4 * 4);
    float* scaleb = (float*)alloc(1024);
    float* shiftb = (float*)alloc(1024);
    unsigned short* hbuf = (unsigned short*)alloc((size_t)N_NODES * 256 * 2);  // bf16
    float* obuf = (float*)alloc((size_t)N_NODES * 256 * 4);
    float* rbuf = (float*)alloc((size_t)N_NODES * 256 * 4);
    float* xout = (float*)alloc((size_t)N_NODES * 64 * 4);

    // --- CSR by dst ---
    hipMemsetAsync(counts, 0, zero_bytes, stream);
    k_hist<<<(ETOT + 255) / 256, 256, 0, stream>>>(ei, counts);
    k_scan<<<1, 1024, 0, stream>>>(counts, offs, cursor);
    k_scatter<<<(ETOT + 255) / 256, 256, 0, stream>>>(ei, cursor, csr_src);

    const int tile64_blocks = ((N_NODES + 63) / 64) * 4;  // 1252
    const int node_blocks = (N_NODES + 3) / 4;            // 5000
    const int red_blocks = (N_NODES + 255) / 256;
    const int final_blocks = N_NODES / 32;                // 625

    auto run_block = [&](const float* xin, int base) {
        const float* W1 = (const float*)d_in[base + 0];
        const float* a1s = (const float*)d_in[base + 1];
        const float* a1d = (const float*)d_in[base + 2];
        const float* b1 = (const float*)d_in[base + 3];
        const float* g1 = (const float*)d_in[base + 4];
        const float* be1 = (const float*)d_in[base + 5];
        const float* W2 = (const float*)d_in[base + 6];
        const float* a2s = (const float*)d_in[base + 7];
        const float* a2d = (const float*)d_in[base + 8];
        const float* b2 = (const float*)d_in[base + 9];
        const float* g2 = (const float*)d_in[base + 10];
        const float* be2 = (const float*)d_in[base + 11];
        const float* Wr = (const float*)d_in[base + 12];
        const float* br = (const float*)d_in[base + 13];
        const float* Wf = (const float*)d_in[base + 14];
        const float* bf = (const float*)d_in[base + 15];

        k_gemm64_dual<<<tile64_blocks, 256, 0, stream>>>(xin, W1, Wr, br, a1s, a1d, hbuf, rbuf, alS, alD);
        k_agg<4><<<node_blocks, 256, 0, stream>>>(hbuf, alS, alD, offs, csr_src, b1, obuf);
        k_bnstats_fin<<<256, 256, 0, stream>>>(obuf, bnsum, bnsq, g1, be1, scaleb, shiftb, bncnt);
        k_gemm256<<<tile64_blocks, 256, 0, stream>>>(obuf, scaleb, shiftb, W2, a2s, a2d, hbuf, alSp, alDp);
        k_alred<<<red_blocks, 256, 0, stream>>>(alSp, alDp, alS, alD);
        k_agg<1><<<node_blocks, 256, 0, stream>>>(hbuf, alS, alD, offs, csr_src, b2, obuf);
        k_bnstats_fin<<<256, 256, 0, stream>>>(obuf, bnsum, bnsq, g2, be2, scaleb, shiftb, bncnt);
        k_gemm_final<<<final_blocks, 256, 0, stream>>>(obuf, scaleb, shiftb, rbuf, Wf, bf, xout);
    };

    run_block(x0, 3);
    run_block(xout, 19);

    k_pool_head<<<G_GROUPS, 256, 0, stream>>>(xout, batch, Wh1, bh1, Wh2, bh2, (float*)d_out);
}

// Round 12
// 635.113 us; speedup vs baseline: 1.1630x; 1.0630x over previous
//
#include <hip/hip_runtime.h>

#define N_NODES 20000
#define N_EDGES 320000
#define ETOT (N_EDGES + N_NODES)
#define G_GROUPS 64

typedef __attribute__((ext_vector_type(8))) short bf16x8;
typedef __attribute__((ext_vector_type(4))) float f32x4;

// bf16 helpers (RNE)
__device__ __forceinline__ unsigned short f2bf(float f) {
    unsigned int u = __float_as_uint(f);
    u += 0x7fffu + ((u >> 16) & 1u);
    return (unsigned short)(u >> 16);
}
__device__ __forceinline__ float bf2f(unsigned short v) {
    return __uint_as_float(((unsigned int)v) << 16);
}
__device__ __forceinline__ unsigned int pack2bf(float a, float b) {
    return (unsigned int)f2bf(a) | ((unsigned int)f2bf(b) << 16);
}

// ---------------- CSR build ----------------

__global__ __launch_bounds__(256) void k_hist(const int* __restrict__ ei, int* __restrict__ counts) {
    int e = blockIdx.x * 256 + threadIdx.x;
    if (e >= ETOT) return;
    int dst = (e < N_EDGES) ? ei[N_EDGES + e] : (e - N_EDGES);
    atomicAdd(&counts[dst], 1);
}

__global__ __launch_bounds__(1024) void k_scan(const int* __restrict__ counts, int* __restrict__ offs,
                                               int* __restrict__ cursor) {
    __shared__ int sdata[1024];
    const int t = threadIdx.x;
    const int chunk = (N_NODES + 1023) / 1024;  // 20
    int base = t * chunk;
    int s = 0;
    for (int i = 0; i < chunk; i++) { int idx = base + i; if (idx < N_NODES) s += counts[idx]; }
    sdata[t] = s;
    __syncthreads();
    for (int off = 1; off < 1024; off <<= 1) {
        int v = (t >= off) ? sdata[t - off] : 0;
        __syncthreads();
        sdata[t] += v;
        __syncthreads();
    }
    int prefix = (t == 0) ? 0 : sdata[t - 1];
    for (int i = 0; i < chunk; i++) {
        int idx = base + i;
        if (idx < N_NODES) {
            int cv = counts[idx];
            offs[idx] = prefix;
            cursor[idx] = prefix;
            prefix += cv;
        }
    }
    if (t == 1023) offs[N_NODES] = sdata[1023];
}

__global__ __launch_bounds__(256) void k_scatter(const int* __restrict__ ei, int* __restrict__ cursor,
                                                 int* __restrict__ csr_src) {
    int e = blockIdx.x * 256 + threadIdx.x;
    if (e >= ETOT) return;
    int src = (e < N_EDGES) ? ei[e] : (e - N_EDGES);
    int dst = (e < N_EDGES) ? ei[N_EDGES + e] : (e - N_EDGES);
    int p = atomicAdd(&cursor[dst], 1);
    csr_src[p] = src;
}

// ---------------- dual GEMM [N,64]x[64,256], 64x64 tiles, alpha fused (strip==head) ----------------

__global__ __launch_bounds__(256) void k_gemm64_dual(const float* __restrict__ x, const float* __restrict__ W1,
                                                     const float* __restrict__ Wr, const float* __restrict__ br,
                                                     const float* __restrict__ a_s, const float* __restrict__ a_d,
                                                     unsigned short* __restrict__ hbf, float* __restrict__ res,
                                                     float* __restrict__ alS, float* __restrict__ alD) {
    const int rb = blockIdx.x >> 2, cs = blockIdx.x & 3;
    const int row0 = rb * 64;
    const int nrows = min(64, N_NODES - row0);
    const int t = threadIdx.x;
    __shared__ float xs[32 * 68];
    __shared__ float b1s[32 * 64];
    __shared__ float brs[32 * 64];
    const int lane = t & 63;
    const int c0 = (t & 15) * 4;
    const int r0 = (t >> 4) * 4;
    const int rl = (t & 15) | ((t >> 6) << 4);
    const int c4 = (t >> 4) & 3;
    float acc1[4][4] = {}, acc2[4][4] = {};
    for (int k0 = 0; k0 < 64; k0 += 32) {
        if (k0) __syncthreads();
        {
            #pragma unroll
            for (int jj = 0; jj < 2; jj++) {
                int cc = c4 + 4 * jj;
                float4 v = {0.f, 0.f, 0.f, 0.f};
                if (rl < nrows) v = *(const float4*)(x + (row0 + rl) * 64 + k0 + cc * 4);
                xs[(cc * 4 + 0) * 68 + rl] = v.x;
                xs[(cc * 4 + 1) * 68 + rl] = v.y;
                xs[(cc * 4 + 2) * 68 + rl] = v.z;
                xs[(cc * 4 + 3) * 68 + rl] = v.w;
            }
        }
        {
            int cc = (t & 15) * 4;
            int k = t >> 4;
            #pragma unroll
            for (int pass = 0; pass < 2; pass++, k += 16) {
                *(float4*)(b1s + k * 64 + cc) = *(const float4*)(W1 + (k0 + k) * 256 + cs * 64 + cc);
                *(float4*)(brs + k * 64 + cc) = *(const float4*)(Wr + (k0 + k) * 256 + cs * 64 + cc);
            }
        }
        __syncthreads();
        #pragma unroll 8
        for (int k = 0; k < 32; k++) {
            float4 av = *(const float4*)(xs + k * 68 + r0);
            float4 b1 = *(const float4*)(b1s + k * 64 + c0);
            float4 b2 = *(const float4*)(brs + k * 64 + c0);
            float a[4] = {av.x, av.y, av.z, av.w};
            #pragma unroll
            for (int i = 0; i < 4; i++) {
                acc1[i][0] += a[i] * b1.x; acc1[i][1] += a[i] * b1.y;
                acc1[i][2] += a[i] * b1.z; acc1[i][3] += a[i] * b1.w;
                acc2[i][0] += a[i] * b2.x; acc2[i][1] += a[i] * b2.y;
                acc2[i][2] += a[i] * b2.z; acc2[i][3] += a[i] * b2.w;
            }
        }
    }
    const int gcol = cs * 64 + c0;
    float4 bv = *(const float4*)(br + gcol);
    float4 asv = *(const float4*)(a_s + gcol);
    float4 adv = *(const float4*)(a_d + gcol);
    #pragma unroll
    for (int i = 0; i < 4; i++) {
        int gr = row0 + r0 + i;
        bool ok = (r0 + i) < nrows;
        float4 o1 = {acc1[i][0], acc1[i][1], acc1[i][2], acc1[i][3]};
        if (ok) {
            ushort4 hq = {f2bf(o1.x), f2bf(o1.y), f2bf(o1.z), f2bf(o1.w)};
            *(ushort4*)(hbf + gr * 256 + gcol) = hq;
            float4 o2 = {acc2[i][0] + bv.x, acc2[i][1] + bv.y, acc2[i][2] + bv.z, acc2[i][3] + bv.w};
            *(float4*)(res + gr * 256 + gcol) = o2;
        }
        float ps = o1.x * asv.x + o1.y * asv.y + o1.z * asv.z + o1.w * asv.w;
        float pd = o1.x * adv.x + o1.y * adv.y + o1.z * adv.z + o1.w * adv.w;
        #pragma unroll
        for (int off = 8; off > 0; off >>= 1) {
            ps += __shfl_down(ps, off);
            pd += __shfl_down(pd, off);
        }
        if (((lane & 15) == 0) && ok) {
            alS[gr * 4 + cs] = ps;
            alD[gr * 4 + cs] = pd;
        }
    }
}

// ---------------- CSR softmax-aggregation on bf16 h, inline fp32 edge weights ----------------

template <int H>
__global__ __launch_bounds__(256) void k_agg(const unsigned short* __restrict__ hbf, const float* __restrict__ alS,
                                             const float* __restrict__ alD, const int* __restrict__ offs,
                                             const int* __restrict__ csr_src, const float* __restrict__ bias,
                                             float* __restrict__ out) {
    int node = blockIdx.x * 4 + (threadIdx.x >> 6);
    int lane = threadIdx.x & 63;
    if (node >= N_NODES) return;
    const int head = (H == 4) ? (lane >> 4) : 0;
    const float ald = alD[node * H + head];
    int e0 = offs[node], e1 = offs[node + 1];
    const unsigned short* hp = hbf + lane * 4;
    float den = 0.f, a0 = 0.f, a1 = 0.f, a2 = 0.f, a3 = 0.f;
    int e = e0;
    for (; e + 8 <= e1; e += 8) {
        int s[8];
        #pragma unroll
        for (int i = 0; i < 8; i++) s[i] = csr_src[e + i];
        ushort4 hq[8];
        #pragma unroll
        for (int i = 0; i < 8; i++) hq[i] = *(const ushort4*)(hp + s[i] * 256);
        float w[8];
        #pragma unroll
        for (int i = 0; i < 8; i++) {
            float v = alS[s[i] * H + head] + ald;
            v = (v > 0.f) ? v : 0.2f * v;
            w[i] = __expf(v);
        }
        #pragma unroll
        for (int i = 0; i < 8; i++) {
            den += w[i];
            a0 += w[i] * bf2f(hq[i].x); a1 += w[i] * bf2f(hq[i].y);
            a2 += w[i] * bf2f(hq[i].z); a3 += w[i] * bf2f(hq[i].w);
        }
    }
    for (; e < e1; e++) {
        int s = csr_src[e];
        float v = alS[s * H + head] + ald;
        v = (v > 0.f) ? v : 0.2f * v;
        float w = __expf(v);
        ushort4 hq = *(const ushort4*)(hp + s * 256);
        den += w;
        a0 += w * bf2f(hq.x); a1 += w * bf2f(hq.y); a2 += w * bf2f(hq.z); a3 += w * bf2f(hq.w);
    }
    float inv = 1.f / den;
    const float4 bv = *(const float4*)(bias + lane * 4);
    float4 o = {a0 * inv + bv.x, a1 * inv + bv.y, a2 * inv + bv.z, a3 * inv + bv.w};
    *(float4*)(out + node * 256 + lane * 4) = o;
}

// ---------------- BatchNorm: stats + finalize fused (last-block-done) ----------------

__global__ __launch_bounds__(256) void k_bnstats_fin(const float* __restrict__ x, float* __restrict__ sum,
                                                     float* __restrict__ sumsq, const float* __restrict__ g,
                                                     const float* __restrict__ be, float* __restrict__ scale,
                                                     float* __restrict__ shift, int* __restrict__ counter) {
    const int c = threadIdx.x;
    float s = 0.f, q = 0.f;
    for (int r = blockIdx.x; r < N_NODES; r += gridDim.x) {
        float v = x[r * 256 + c];
        s += v; q += v * v;
    }
    atomicAdd(&sum[c], s);
    atomicAdd(&sumsq[c], q);
    __threadfence();
    __syncthreads();
    __shared__ int lastFlag;
    if (c == 0) lastFlag = (atomicAdd(counter, 1) == (int)gridDim.x - 1);
    __syncthreads();
    if (lastFlag) {
        float S = atomicAdd(&sum[c], 0.f);
        float Q = atomicAdd(&sumsq[c], 0.f);
        float mu = S * (1.f / N_NODES);
        float var = Q * (1.f / N_NODES) - mu * mu;
        float sc = g[c] * rsqrtf(var + 1e-5f);
        scale[c] = sc;
        shift[c] = be[c] - mu * sc;
        sum[c] = 0.f;
        sumsq[c] = 0.f;
        if (c == 0) *counter = 0;
    }
}

// ---------------- pre-pack W2 [256][256] fp32 -> B-fragment-major bf16 ----------------
// Bf[((kt*16 + nt)*64 + l)*8 + j] = bf16(W[(kt*32 + (l>>4)*8 + j)*256 + nt*16 + (l&15)])

__global__ __launch_bounds__(256) void k_prepB(const float* __restrict__ W, unsigned short* __restrict__ Bf) {
    int s = blockIdx.x * 256 + threadIdx.x;  // [0, 8192)
    int l = s & 63;
    int nt = (s >> 6) & 15;
    int kt = s >> 10;
    int n = nt * 16 + (l & 15);
    int kb = kt * 32 + (l >> 4) * 8;
    float v[8];
    #pragma unroll
    for (int j = 0; j < 8; j++) v[j] = W[(kb + j) * 256 + n];
    uint4 q = {pack2bf(v[0], v[1]), pack2bf(v[2], v[3]), pack2bf(v[4], v[5]), pack2bf(v[6], v[7])};
    *(uint4*)(Bf + s * 8) = q;
}

// ---------------- MFMA GEMM: bf16(relu(bn(A))) @ bf16(W2), [N,256]x[256,256] ----------------

__global__ __launch_bounds__(256) void k_gemm256_mfma(const float* __restrict__ A, const float* __restrict__ scale,
                                                      const float* __restrict__ shift,
                                                      const unsigned short* __restrict__ Bf,
                                                      const float* __restrict__ a_s, const float* __restrict__ a_d,
                                                      unsigned short* __restrict__ C, float* __restrict__ alSp,
                                                      float* __restrict__ alDp) {
    const int rb = blockIdx.x >> 2, cs = blockIdx.x & 3;
    const int row0 = rb * 64;
    const int nrows = min(64, N_NODES - row0);
    const int t = threadIdx.x;
    const int w = t >> 6;
    const int l = t & 63;
    const int quad = l >> 4;
    const int colLocal = l & 15;
    __shared__ unsigned short As[2 * 4 * 64 * 8];  // [kt2][mt][lane][8] bf16, 8 KB
    __shared__ float scs[256], shs[256];
    scs[t] = scale[t];
    shs[t] = shift[t];

    const int ntg = cs * 4 + w;  // global n-tile 0..15
    bf16x8 bfrag[8];
    #pragma unroll
    for (int kt = 0; kt < 8; kt++)
        bfrag[kt] = *(const bf16x8*)(Bf + ((kt * 16 + ntg) * 64 + l) * 8);

    f32x4 acc[4];
    #pragma unroll
    for (int mt = 0; mt < 4; mt++) acc[mt] = (f32x4){0.f, 0.f, 0.f, 0.f};

    const int smt = (t >> 6) & 3;
    const int sm = smt * 16 + (l & 15);
    const int skoff = (l >> 4) * 8;

    for (int kc = 0; kc < 4; kc++) {
        __syncthreads();
        #pragma unroll
        for (int kt2 = 0; kt2 < 2; kt2++) {
            int k = kc * 64 + kt2 * 32 + skoff;
            float4 v0 = {0.f, 0.f, 0.f, 0.f}, v1 = {0.f, 0.f, 0.f, 0.f};
            if (sm < nrows) {
                v0 = *(const float4*)(A + (row0 + sm) * 256 + k);
                v1 = *(const float4*)(A + (row0 + sm) * 256 + k + 4);
                v0.x = fmaxf(v0.x * scs[k + 0] + shs[k + 0], 0.f);
                v0.y = fmaxf(v0.y * scs[k + 1] + shs[k + 1], 0.f);
                v0.z = fmaxf(v0.z * scs[k + 2] + shs[k + 2], 0.f);
                v0.w = fmaxf(v0.w * scs[k + 3] + shs[k + 3], 0.f);
                v1.x = fmaxf(v1.x * scs[k + 4] + shs[k + 4], 0.f);
                v1.y = fmaxf(v1.y * scs[k + 5] + shs[k + 5], 0.f);
                v1.z = fmaxf(v1.z * scs[k + 6] + shs[k + 6], 0.f);
                v1.w = fmaxf(v1.w * scs[k + 7] + shs[k + 7], 0.f);
            }
            uint4 q = {pack2bf(v0.x, v0.y), pack2bf(v0.z, v0.w), pack2bf(v1.x, v1.y), pack2bf(v1.z, v1.w)};
            *(uint4*)(As + ((kt2 * 4 + smt) * 64 + l) * 8) = q;
        }
        __syncthreads();
        #pragma unroll
        for (int kt2 = 0; kt2 < 2; kt2++) {
            int ktg = kc * 2 + kt2;
            #pragma unroll
            for (int mt = 0; mt < 4; mt++) {
                bf16x8 af = *(const bf16x8*)(As + ((kt2 * 4 + mt) * 64 + l) * 8);
                acc[mt] = __builtin_amdgcn_mfma_f32_16x16x32_bf16(af, bfrag[ktg], acc[mt], 0, 0, 0);
            }
        }
    }

    const int col = cs * 64 + w * 16 + colLocal;
    const float asv = a_s[col];
    const float adv = a_d[col];
    #pragma unroll
    for (int mt = 0; mt < 4; mt++) {
        #pragma unroll
        for (int r = 0; r < 4; r++) {
            float v = acc[mt][r];
            int lr = mt * 16 + quad * 4 + r;
            bool ok = lr < nrows;
            int row = row0 + lr;
            if (ok) C[row * 256 + col] = f2bf(v);
            float ps = v * asv, pd = v * adv;
            #pragma unroll
            for (int off = 1; off < 16; off <<= 1) {
                ps += __shfl_xor(ps, off);
                pd += __shfl_xor(pd, off);
            }
            if (colLocal == 0 && ok) {
                alSp[ntg * N_NODES + row] = ps;
                alDp[ntg * N_NODES + row] = pd;
            }
        }
    }
}

__global__ __launch_bounds__(256) void k_alred(const float* __restrict__ alSp, const float* __restrict__ alDp,
                                               float* __restrict__ alS, float* __restrict__ alD) {
    int n = blockIdx.x * 256 + threadIdx.x;
    if (n >= N_NODES) return;
    float s = 0.f, d = 0.f;
    #pragma unroll
    for (int i = 0; i < 16; i++) {
        s += alSp[i * N_NODES + n];
        d += alDp[i * N_NODES + n];
    }
    alS[n] = s;
    alD[n] = d;
}

// ---------------- final GEMM ((relu(bn(A))+res)*invsqrt2)@Wf+bf -> [N,64], 32x64 tiles ----------------

__global__ __launch_bounds__(256) void k_gemm_final(const float* __restrict__ A, const float* __restrict__ scale,
                                                    const float* __restrict__ shift, const float* __restrict__ res,
                                                    const float* __restrict__ B, const float* __restrict__ bias,
                                                    float* __restrict__ y) {
    const int row0 = blockIdx.x * 32;
    const int t = threadIdx.x;
    const float INVS = 0.70710678118654752440f;
    __shared__ float xs[32 * 36];
    __shared__ float bs[32 * 64];
    __shared__ float scs[256], shs[256];
    scs[t] = scale[t];
    shs[t] = shift[t];
    const int rf = (t & 15) | ((t >> 7) << 4);
    const int cf = (t >> 4) & 7;
    const int c0 = (t & 15) * 4;
    const int r0 = (t >> 4) * 2;
    float acc[2][4] = {};
    for (int k0 = 0; k0 < 256; k0 += 32) {
        __syncthreads();
        {
            int kcol = k0 + cf * 4;
            int gi = (row0 + rf) * 256 + kcol;
            float4 v = *(const float4*)(A + gi);
            float4 rv = *(const float4*)(res + gi);
            xs[(cf * 4 + 0) * 36 + rf] = (fmaxf(v.x * scs[kcol + 0] + shs[kcol + 0], 0.f) + rv.x) * INVS;
            xs[(cf * 4 + 1) * 36 + rf] = (fmaxf(v.y * scs[kcol + 1] + shs[kcol + 1], 0.f) + rv.y) * INVS;
            xs[(cf * 4 + 2) * 36 + rf] = (fmaxf(v.z * scs[kcol + 2] + shs[kcol + 2], 0.f) + rv.z) * INVS;
            xs[(cf * 4 + 3) * 36 + rf] = (fmaxf(v.w * scs[kcol + 3] + shs[kcol + 3], 0.f) + rv.w) * INVS;
        }
        {
            int cc = (t & 15) * 4;
            int k = t >> 4;
            #pragma unroll
            for (int pass = 0; pass < 2; pass++, k += 16) {
                *(float4*)(bs + k * 64 + cc) = *(const float4*)(B + (k0 + k) * 64 + cc);
            }
        }
        __syncthreads();
        #pragma unroll 8
        for (int k = 0; k < 32; k++) {
            float2 av = *(const float2*)(xs + k * 36 + r0);
            float4 bv = *(const float4*)(bs + k * 64 + c0);
            acc[0][0] += av.x * bv.x; acc[0][1] += av.x * bv.y;
            acc[0][2] += av.x * bv.z; acc[0][3] += av.x * bv.w;
            acc[1][0] += av.y * bv.x; acc[1][1] += av.y * bv.y;
            acc[1][2] += av.y * bv.z; acc[1][3] += av.y * bv.w;
        }
    }
    float4 bv = *(const float4*)(bias + c0);
    #pragma unroll
    for (int i = 0; i < 2; i++) {
        int gr = row0 + r0 + i;
        float4 o = {acc[i][0] + bv.x, acc[i][1] + bv.y, acc[i][2] + bv.z, acc[i][3] + bv.w};
        *(float4*)(y + gr * 64 + c0) = o;
    }
}

// ---------------- fused mean-pool (sorted batch) + MLP head ----------------

__global__ __launch_bounds__(256) void k_pool_head(const float* __restrict__ x, const int* __restrict__ batch,
                                                   const float* __restrict__ Wh1, const float* __restrict__ bh1,
                                                   const float* __restrict__ Wh2, const float* __restrict__ bh2,
                                                   float* __restrict__ out) {
    const int g = blockIdx.x;
    const int t = threadIdx.x;
    int lo = 0, hi = N_NODES;
    while (lo < hi) { int mid = (lo + hi) >> 1; if (batch[mid] < g) lo = mid + 1; else hi = mid; }
    int start = lo;
    hi = N_NODES;
    while (lo < hi) { int mid = (lo + hi) >> 1; if (batch[mid] < g + 1) lo = mid + 1; else hi = mid; }
    int end = lo;
    float cnt = (float)(end - start);

    __shared__ float part[256];
    __shared__ float p[64];
    __shared__ float hrow[256];
    const int c = t & 63;
    float s = 0.f;
    for (int r = start + (t >> 6); r < end; r += 4) s += x[r * 64 + c];
    part[t] = s;
    __syncthreads();
    if (t < 64) {
        float v = part[t] + part[t + 64] + part[t + 128] + part[t + 192];
        p[t] = v / fmaxf(cnt, 1.f);
    }
    __syncthreads();
    float a = bh1[t];
    #pragma unroll 8
    for (int k = 0; k < 64; k++) a += p[k] * Wh1[k * 256 + t];
    hrow[t] = fmaxf(a, 0.f);
    __syncthreads();
    if (t < 128) {
        float o = bh2[t];
        #pragma unroll 8
        for (int k = 0; k < 256; k++) o += hrow[k] * Wh2[k * 128 + t];
        out[g * 128 + t] = o;
    }
}

// ---------------- host ----------------

extern "C" void kernel_launch(void* const* d_in, const int* in_sizes, int n_in,
                              void* d_out, int out_size, void* d_ws, size_t ws_size,
                              hipStream_t stream) {
    (void)in_sizes; (void)n_in; (void)out_size; (void)ws_size;
    const float* x0 = (const float*)d_in[0];
    const int* ei = (const int*)d_in[1];
    const int* batch = (const int*)d_in[2];
    const float* Wh1 = (const float*)d_in[35];
    const float* bh1 = (const float*)d_in[36];
    const float* Wh2 = (const float*)d_in[37];
    const float* bh2 = (const float*)d_in[38];

    char* p = (char*)d_ws;
    auto alloc = [&](size_t bytes) -> void* {
        void* r = (void*)p;
        p += (bytes + 255) & ~(size_t)255;
        return r;
    };
    int* counts = (int*)alloc((size_t)N_NODES * 4);
    float* bnsum = (float*)alloc(2048);
    float* bnsq = bnsum + 256;
    int* bncnt = (int*)alloc(256);
    const size_t zero_bytes = (((size_t)N_NODES * 4 + 255) & ~(size_t)255) + 2048 + 256;
    int* offs = (int*)alloc((size_t)(N_NODES + 1) * 4);
    int* cursor = (int*)alloc((size_t)N_NODES * 4);
    int* csr_src = (int*)alloc((size_t)ETOT * 4);
    float* alS = (float*)alloc((size_t)N_NODES * 4 * 4);
    float* alD = (float*)alloc((size_t)N_NODES * 4 * 4);
    float* alSp = (float*)alloc((size_t)N_NODES * 16 * 4);
    float* alDp = (float*)alloc((size_t)N_NODES * 16 * 4);
    float* scaleb = (float*)alloc(1024);
    float* shiftb = (float*)alloc(1024);
    unsigned short* hbuf = (unsigned short*)alloc((size_t)N_NODES * 256 * 2);
    float* obuf = (float*)alloc((size_t)N_NODES * 256 * 4);
    float* rbuf = (float*)alloc((size_t)N_NODES * 256 * 4);
    float* xout = (float*)alloc((size_t)N_NODES * 64 * 4);
    unsigned short* Bf0 = (unsigned short*)alloc(256 * 256 * 2);
    unsigned short* Bf1 = (unsigned short*)alloc(256 * 256 * 2);

    // --- CSR by dst + W2 fragment pre-pack ---
    hipMemsetAsync(counts, 0, zero_bytes, stream);
    k_hist<<<(ETOT + 255) / 256, 256, 0, stream>>>(ei, counts);
    k_scan<<<1, 1024, 0, stream>>>(counts, offs, cursor);
    k_scatter<<<(ETOT + 255) / 256, 256, 0, stream>>>(ei, cursor, csr_src);
    k_prepB<<<32, 256, 0, stream>>>((const float*)d_in[3 + 6], Bf0);
    k_prepB<<<32, 256, 0, stream>>>((const float*)d_in[19 + 6], Bf1);

    const int tile64_blocks = ((N_NODES + 63) / 64) * 4;  // 1252
    const int node_blocks = (N_NODES + 3) / 4;            // 5000
    const int red_blocks = (N_NODES + 255) / 256;
    const int final_blocks = N_NODES / 32;                // 625

    auto run_block = [&](const float* xin, int base, const unsigned short* Bf) {
        const float* W1 = (const float*)d_in[base + 0];
        const float* a1s = (const float*)d_in[base + 1];
        const float* a1d = (const float*)d_in[base + 2];
        const float* b1 = (const float*)d_in[base + 3];
        const float* g1 = (const float*)d_in[base + 4];
        const float* be1 = (const float*)d_in[base + 5];
        const float* a2s = (const float*)d_in[base + 7];
        const float* a2d = (const float*)d_in[base + 8];
        const float* b2 = (const float*)d_in[base + 9];
        const float* g2 = (const float*)d_in[base + 10];
        const float* be2 = (const float*)d_in[base + 11];
        const float* Wr = (const float*)d_in[base + 12];
        const float* br = (const float*)d_in[base + 13];
        const float* Wf = (const float*)d_in[base + 14];
        const float* bf = (const float*)d_in[base + 15];

        k_gemm64_dual<<<tile64_blocks, 256, 0, stream>>>(xin, W1, Wr, br, a1s, a1d, hbuf, rbuf, alS, alD);
        k_agg<4><<<node_blocks, 256, 0, stream>>>(hbuf, alS, alD, offs, csr_src, b1, obuf);
        k_bnstats_fin<<<256, 256, 0, stream>>>(obuf, bnsum, bnsq, g1, be1, scaleb, shiftb, bncnt);
        k_gemm256_mfma<<<tile64_blocks, 256, 0, stream>>>(obuf, scaleb, shiftb, Bf, a2s, a2d, hbuf, alSp, alDp);
        k_alred<<<red_blocks, 256, 0, stream>>>(alSp, alDp, alS, alD);
        k_agg<1><<<node_blocks, 256, 0, stream>>>(hbuf, alS, alD, offs, csr_src, b2, obuf);
        k_bnstats_fin<<<256, 256, 0, stream>>>(obuf, bnsum, bnsq, g2, be2, scaleb, shiftb, bncnt);
        k_gemm_final<<<final_blocks, 256, 0, stream>>>(obuf, scaleb, shiftb, rbuf, Wf, bf, xout);
    };

    run_block(x0, 3, Bf0);
    run_block(xout, 19, Bf1);

    k_pool_head<<<G_GROUPS, 256, 0, stream>>>(xout, batch, Wh1, bh1, Wh2, bh2, (float*)d_out);
}

// Round 13
// 634.138 us; speedup vs baseline: 1.1648x; 1.0015x over previous
//
#include <hip/hip_runtime.h>

#define N_NODES 20000
#define N_EDGES 320000
#define ETOT (N_EDGES + N_NODES)
#define G_GROUPS 64

typedef __attribute__((ext_vector_type(8))) short bf16x8;
typedef __attribute__((ext_vector_type(4))) float f32x4;

// bf16 helpers (RNE)
__device__ __forceinline__ unsigned short f2bf(float f) {
    unsigned int u = __float_as_uint(f);
    u += 0x7fffu + ((u >> 16) & 1u);
    return (unsigned short)(u >> 16);
}
__device__ __forceinline__ float bf2f(unsigned short v) {
    return __uint_as_float(((unsigned int)v) << 16);
}
__device__ __forceinline__ unsigned int pack2bf(float a, float b) {
    return (unsigned int)f2bf(a) | ((unsigned int)f2bf(b) << 16);
}

// ---------------- CSR build ----------------

__global__ __launch_bounds__(256) void k_hist(const int* __restrict__ ei, int* __restrict__ counts) {
    int e = blockIdx.x * 256 + threadIdx.x;
    if (e >= ETOT) return;
    int dst = (e < N_EDGES) ? ei[N_EDGES + e] : (e - N_EDGES);
    atomicAdd(&counts[dst], 1);
}

__global__ __launch_bounds__(1024) void k_scan(const int* __restrict__ counts, int* __restrict__ offs,
                                               int* __restrict__ cursor) {
    __shared__ int sdata[1024];
    const int t = threadIdx.x;
    const int chunk = (N_NODES + 1023) / 1024;  // 20
    int base = t * chunk;
    int s = 0;
    for (int i = 0; i < chunk; i++) { int idx = base + i; if (idx < N_NODES) s += counts[idx]; }
    sdata[t] = s;
    __syncthreads();
    for (int off = 1; off < 1024; off <<= 1) {
        int v = (t >= off) ? sdata[t - off] : 0;
        __syncthreads();
        sdata[t] += v;
        __syncthreads();
    }
    int prefix = (t == 0) ? 0 : sdata[t - 1];
    for (int i = 0; i < chunk; i++) {
        int idx = base + i;
        if (idx < N_NODES) {
            int cv = counts[idx];
            offs[idx] = prefix;
            cursor[idx] = prefix;
            prefix += cv;
        }
    }
    if (t == 1023) offs[N_NODES] = sdata[1023];
}

__global__ __launch_bounds__(256) void k_scatter(const int* __restrict__ ei, int* __restrict__ cursor,
                                                 int* __restrict__ csr_src) {
    int e = blockIdx.x * 256 + threadIdx.x;
    if (e >= ETOT) return;
    int src = (e < N_EDGES) ? ei[e] : (e - N_EDGES);
    int dst = (e < N_EDGES) ? ei[N_EDGES + e] : (e - N_EDGES);
    int p = atomicAdd(&cursor[dst], 1);
    csr_src[p] = src;
}

// ---------------- pre-pack W [K][256] fp32 -> B-fragment-major bf16 ----------------
// frag-lane s: l=s&63, nt=(s>>6)&15, kt=s>>10; Bf[s*8+j] = bf16(W[(kt*32+(l>>4)*8+j)*256 + nt*16+(l&15)])

__global__ __launch_bounds__(256) void k_prepB(const float* __restrict__ W, unsigned short* __restrict__ Bf,
                                               int nfrag) {
    int s = blockIdx.x * 256 + threadIdx.x;
    if (s >= nfrag) return;
    int l = s & 63;
    int nt = (s >> 6) & 15;
    int kt = s >> 10;
    int n = nt * 16 + (l & 15);
    int kb = kt * 32 + (l >> 4) * 8;
    float v[8];
    #pragma unroll
    for (int j = 0; j < 8; j++) v[j] = W[(kb + j) * 256 + n];
    uint4 q = {pack2bf(v[0], v[1]), pack2bf(v[2], v[3]), pack2bf(v[4], v[5]), pack2bf(v[6], v[7])};
    *(uint4*)(Bf + s * 8) = q;
}

// ---------------- MFMA dual GEMM [N,64]x[64,256] (W1 & Wr), 64x64 tiles, alpha fused ----------------
// wave w = n-tile ntg=cs*4+w; 4 m-tiles; K=64 = 2 k-frags; 16 MFMA/wave.
// x staged once to LDS bf16 fragment-major; alpha (head==cs) reduced cross-wave in LDS.

__global__ __launch_bounds__(256) void k_gemm64_dual(const float* __restrict__ x,
                                                     const unsigned short* __restrict__ Bf1,
                                                     const unsigned short* __restrict__ Bfr,
                                                     const float* __restrict__ br,
                                                     const float* __restrict__ a_s, const float* __restrict__ a_d,
                                                     unsigned short* __restrict__ hbf, float* __restrict__ res,
                                                     float* __restrict__ alS, float* __restrict__ alD) {
    const int rb = blockIdx.x >> 2, cs = blockIdx.x & 3;
    const int row0 = rb * 64;
    const int nrows = min(64, N_NODES - row0);
    const int t = threadIdx.x;
    const int w = t >> 6;
    const int l = t & 63;
    const int quad = l >> 4;
    const int colLocal = l & 15;
    __shared__ unsigned short As[8 * 64 * 8];  // [kt*4+mt][lane][8] bf16, 8 KB
    __shared__ float alsm[4][64], aldm[4][64];

    const int ntg = cs * 4 + w;
    bf16x8 b1f[2], brf[2];
    #pragma unroll
    for (int kt = 0; kt < 2; kt++) {
        b1f[kt] = *(const bf16x8*)(Bf1 + ((kt * 16 + ntg) * 64 + l) * 8);
        brf[kt] = *(const bf16x8*)(Bfr + ((kt * 16 + ntg) * 64 + l) * 8);
    }

    // stage x tile: thread t stages frag-groups 2w and 2w+1
    #pragma unroll
    for (int gi = 0; gi < 2; gi++) {
        int g = 2 * w + gi;           // 0..7
        int kt = g >> 2, mt = g & 3;
        int sm = mt * 16 + (l & 15);
        int koff = kt * 32 + (l >> 4) * 8;
        float4 v0 = {0.f, 0.f, 0.f, 0.f}, v1 = {0.f, 0.f, 0.f, 0.f};
        if (sm < nrows) {
            v0 = *(const float4*)(x + (row0 + sm) * 64 + koff);
            v1 = *(const float4*)(x + (row0 + sm) * 64 + koff + 4);
        }
        uint4 q = {pack2bf(v0.x, v0.y), pack2bf(v0.z, v0.w), pack2bf(v1.x, v1.y), pack2bf(v1.z, v1.w)};
        *(uint4*)(As + (g * 64 + l) * 8) = q;
    }
    __syncthreads();

    f32x4 acc1[4], acc2[4];
    #pragma unroll
    for (int mt = 0; mt < 4; mt++) {
        acc1[mt] = (f32x4){0.f, 0.f, 0.f, 0.f};
        acc2[mt] = (f32x4){0.f, 0.f, 0.f, 0.f};
    }
    #pragma unroll
    for (int kt = 0; kt < 2; kt++) {
        #pragma unroll
        for (int mt = 0; mt < 4; mt++) {
            bf16x8 af = *(const bf16x8*)(As + ((kt * 4 + mt) * 64 + l) * 8);
            acc1[mt] = __builtin_amdgcn_mfma_f32_16x16x32_bf16(af, b1f[kt], acc1[mt], 0, 0, 0);
            acc2[mt] = __builtin_amdgcn_mfma_f32_16x16x32_bf16(af, brf[kt], acc2[mt], 0, 0, 0);
        }
    }

    // epilogue
    const int col = cs * 64 + w * 16 + colLocal;
    const float brv = br[col];
    const float asv = a_s[col];
    const float adv = a_d[col];
    #pragma unroll
    for (int mt = 0; mt < 4; mt++) {
        #pragma unroll
        for (int r = 0; r < 4; r++) {
            float v1 = acc1[mt][r];
            int lr = mt * 16 + quad * 4 + r;
            bool ok = lr < nrows;
            int row = row0 + lr;
            if (ok) {
                hbf[row * 256 + col] = f2bf(v1);
                res[row * 256 + col] = acc2[mt][r] + brv;
            }
            float ps = v1 * asv, pd = v1 * adv;
            #pragma unroll
            for (int off = 1; off < 16; off <<= 1) {
                ps += __shfl_xor(ps, off);
                pd += __shfl_xor(pd, off);
            }
            if (colLocal == 0) {
                alsm[w][lr] = ps;
                aldm[w][lr] = pd;
            }
        }
    }
    __syncthreads();
    if (t < 64 && t < nrows) {
        float s = (alsm[0][t] + alsm[1][t]) + (alsm[2][t] + alsm[3][t]);
        float d = (aldm[0][t] + aldm[1][t]) + (aldm[2][t] + aldm[3][t]);
        alS[(row0 + t) * 4 + cs] = s;
        alD[(row0 + t) * 4 + cs] = d;
    }
}

// ---------------- CSR softmax-aggregation on bf16 h, inline fp32 edge weights ----------------

template <int H>
__global__ __launch_bounds__(256) void k_agg(const unsigned short* __restrict__ hbf, const float* __restrict__ alS,
                                             const float* __restrict__ alD, const int* __restrict__ offs,
                                             const int* __restrict__ csr_src, const float* __restrict__ bias,
                                             float* __restrict__ out) {
    int node = blockIdx.x * 4 + (threadIdx.x >> 6);
    int lane = threadIdx.x & 63;
    if (node >= N_NODES) return;
    const int head = (H == 4) ? (lane >> 4) : 0;
    const float ald = alD[node * H + head];
    int e0 = offs[node], e1 = offs[node + 1];
    const unsigned short* hp = hbf + lane * 4;
    float den = 0.f, a0 = 0.f, a1 = 0.f, a2 = 0.f, a3 = 0.f;
    int e = e0;
    for (; e + 8 <= e1; e += 8) {
        int s[8];
        #pragma unroll
        for (int i = 0; i < 8; i++) s[i] = csr_src[e + i];
        ushort4 hq[8];
        #pragma unroll
        for (int i = 0; i < 8; i++) hq[i] = *(const ushort4*)(hp + s[i] * 256);
        float w[8];
        #pragma unroll
        for (int i = 0; i < 8; i++) {
            float v = alS[s[i] * H + head] + ald;
            v = (v > 0.f) ? v : 0.2f * v;
            w[i] = __expf(v);
        }
        #pragma unroll
        for (int i = 0; i < 8; i++) {
            den += w[i];
            a0 += w[i] * bf2f(hq[i].x); a1 += w[i] * bf2f(hq[i].y);
            a2 += w[i] * bf2f(hq[i].z); a3 += w[i] * bf2f(hq[i].w);
        }
    }
    for (; e < e1; e++) {
        int s = csr_src[e];
        float v = alS[s * H + head] + ald;
        v = (v > 0.f) ? v : 0.2f * v;
        float w = __expf(v);
        ushort4 hq = *(const ushort4*)(hp + s * 256);
        den += w;
        a0 += w * bf2f(hq.x); a1 += w * bf2f(hq.y); a2 += w * bf2f(hq.z); a3 += w * bf2f(hq.w);
    }
    float inv = 1.f / den;
    const float4 bv = *(const float4*)(bias + lane * 4);
    float4 o = {a0 * inv + bv.x, a1 * inv + bv.y, a2 * inv + bv.z, a3 * inv + bv.w};
    *(float4*)(out + node * 256 + lane * 4) = o;
}

// ---------------- BatchNorm: stats + finalize fused (last-block-done) ----------------

__global__ __launch_bounds__(256) void k_bnstats_fin(const float* __restrict__ x, float* __restrict__ sum,
                                                     float* __restrict__ sumsq, const float* __restrict__ g,
                                                     const float* __restrict__ be, float* __restrict__ scale,
                                                     float* __restrict__ shift, int* __restrict__ counter) {
    const int c = threadIdx.x;
    float s = 0.f, q = 0.f;
    for (int r = blockIdx.x; r < N_NODES; r += gridDim.x) {
        float v = x[r * 256 + c];
        s += v; q += v * v;
    }
    atomicAdd(&sum[c], s);
    atomicAdd(&sumsq[c], q);
    __threadfence();
    __syncthreads();
    __shared__ int lastFlag;
    if (c == 0) lastFlag = (atomicAdd(counter, 1) == (int)gridDim.x - 1);
    __syncthreads();
    if (lastFlag) {
        float S = atomicAdd(&sum[c], 0.f);
        float Q = atomicAdd(&sumsq[c], 0.f);
        float mu = S * (1.f / N_NODES);
        float var = Q * (1.f / N_NODES) - mu * mu;
        float sc = g[c] * rsqrtf(var + 1e-5f);
        scale[c] = sc;
        shift[c] = be[c] - mu * sc;
        sum[c] = 0.f;
        sumsq[c] = 0.f;
        if (c == 0) *counter = 0;
    }
}

// ---------------- MFMA GEMM: bf16(relu(bn(A))) @ bf16(W2), [N,256]x[256,256] ----------------

__global__ __launch_bounds__(256) void k_gemm256_mfma(const float* __restrict__ A, const float* __restrict__ scale,
                                                      const float* __restrict__ shift,
                                                      const unsigned short* __restrict__ Bf,
                                                      const float* __restrict__ a_s, const float* __restrict__ a_d,
                                                      unsigned short* __restrict__ C, float* __restrict__ alSp,
                                                      float* __restrict__ alDp) {
    const int rb = blockIdx.x >> 2, cs = blockIdx.x & 3;
    const int row0 = rb * 64;
    const int nrows = min(64, N_NODES - row0);
    const int t = threadIdx.x;
    const int w = t >> 6;
    const int l = t & 63;
    const int quad = l >> 4;
    const int colLocal = l & 15;
    __shared__ unsigned short As[2 * 4 * 64 * 8];  // 8 KB
    __shared__ float scs[256], shs[256];
    scs[t] = scale[t];
    shs[t] = shift[t];

    const int ntg = cs * 4 + w;
    bf16x8 bfrag[8];
    #pragma unroll
    for (int kt = 0; kt < 8; kt++)
        bfrag[kt] = *(const bf16x8*)(Bf + ((kt * 16 + ntg) * 64 + l) * 8);

    f32x4 acc[4];
    #pragma unroll
    for (int mt = 0; mt < 4; mt++) acc[mt] = (f32x4){0.f, 0.f, 0.f, 0.f};

    const int smt = (t >> 6) & 3;
    const int sm = smt * 16 + (l & 15);
    const int skoff = (l >> 4) * 8;

    for (int kc = 0; kc < 4; kc++) {
        __syncthreads();
        #pragma unroll
        for (int kt2 = 0; kt2 < 2; kt2++) {
            int k = kc * 64 + kt2 * 32 + skoff;
            float4 v0 = {0.f, 0.f, 0.f, 0.f}, v1 = {0.f, 0.f, 0.f, 0.f};
            if (sm < nrows) {
                v0 = *(const float4*)(A + (row0 + sm) * 256 + k);
                v1 = *(const float4*)(A + (row0 + sm) * 256 + k + 4);
                v0.x = fmaxf(v0.x * scs[k + 0] + shs[k + 0], 0.f);
                v0.y = fmaxf(v0.y * scs[k + 1] + shs[k + 1], 0.f);
                v0.z = fmaxf(v0.z * scs[k + 2] + shs[k + 2], 0.f);
                v0.w = fmaxf(v0.w * scs[k + 3] + shs[k + 3], 0.f);
                v1.x = fmaxf(v1.x * scs[k + 4] + shs[k + 4], 0.f);
                v1.y = fmaxf(v1.y * scs[k + 5] + shs[k + 5], 0.f);
                v1.z = fmaxf(v1.z * scs[k + 6] + shs[k + 6], 0.f);
                v1.w = fmaxf(v1.w * scs[k + 7] + shs[k + 7], 0.f);
            }
            uint4 q = {pack2bf(v0.x, v0.y), pack2bf(v0.z, v0.w), pack2bf(v1.x, v1.y), pack2bf(v1.z, v1.w)};
            *(uint4*)(As + ((kt2 * 4 + smt) * 64 + l) * 8) = q;
        }
        __syncthreads();
        #pragma unroll
        for (int kt2 = 0; kt2 < 2; kt2++) {
            int ktg = kc * 2 + kt2;
            #pragma unroll
            for (int mt = 0; mt < 4; mt++) {
                bf16x8 af = *(const bf16x8*)(As + ((kt2 * 4 + mt) * 64 + l) * 8);
                acc[mt] = __builtin_amdgcn_mfma_f32_16x16x32_bf16(af, bfrag[ktg], acc[mt], 0, 0, 0);
            }
        }
    }

    const int col = cs * 64 + w * 16 + colLocal;
    const float asv = a_s[col];
    const float adv = a_d[col];
    #pragma unroll
    for (int mt = 0; mt < 4; mt++) {
        #pragma unroll
        for (int r = 0; r < 4; r++) {
            float v = acc[mt][r];
            int lr = mt * 16 + quad * 4 + r;
            bool ok = lr < nrows;
            int row = row0 + lr;
            if (ok) C[row * 256 + col] = f2bf(v);
            float ps = v * asv, pd = v * adv;
            #pragma unroll
            for (int off = 1; off < 16; off <<= 1) {
                ps += __shfl_xor(ps, off);
                pd += __shfl_xor(pd, off);
            }
            if (colLocal == 0 && ok) {
                alSp[ntg * N_NODES + row] = ps;
                alDp[ntg * N_NODES + row] = pd;
            }
        }
    }
}

__global__ __launch_bounds__(256) void k_alred(const float* __restrict__ alSp, const float* __restrict__ alDp,
                                               float* __restrict__ alS, float* __restrict__ alD) {
    int n = blockIdx.x * 256 + threadIdx.x;
    if (n >= N_NODES) return;
    float s = 0.f, d = 0.f;
    #pragma unroll
    for (int i = 0; i < 16; i++) {
        s += alSp[i * N_NODES + n];
        d += alDp[i * N_NODES + n];
    }
    alS[n] = s;
    alD[n] = d;
}

// ---------------- final GEMM ((relu(bn(A))+res)*invsqrt2)@Wf+bf -> [N,64], 32x64 tiles ----------------

__global__ __launch_bounds__(256) void k_gemm_final(const float* __restrict__ A, const float* __restrict__ scale,
                                                    const float* __restrict__ shift, const float* __restrict__ res,
                                                    const float* __restrict__ B, const float* __restrict__ bias,
                                                    float* __restrict__ y) {
    const int row0 = blockIdx.x * 32;
    const int t = threadIdx.x;
    const float INVS = 0.70710678118654752440f;
    __shared__ float xs[32 * 36];
    __shared__ float bs[32 * 64];
    __shared__ float scs[256], shs[256];
    scs[t] = scale[t];
    shs[t] = shift[t];
    const int rf = (t & 15) | ((t >> 7) << 4);
    const int cf = (t >> 4) & 7;
    const int c0 = (t & 15) * 4;
    const int r0 = (t >> 4) * 2;
    float acc[2][4] = {};
    for (int k0 = 0; k0 < 256; k0 += 32) {
        __syncthreads();
        {
            int kcol = k0 + cf * 4;
            int gi = (row0 + rf) * 256 + kcol;
            float4 v = *(const float4*)(A + gi);
            float4 rv = *(const float4*)(res + gi);
            xs[(cf * 4 + 0) * 36 + rf] = (fmaxf(v.x * scs[kcol + 0] + shs[kcol + 0], 0.f) + rv.x) * INVS;
            xs[(cf * 4 + 1) * 36 + rf] = (fmaxf(v.y * scs[kcol + 1] + shs[kcol + 1], 0.f) + rv.y) * INVS;
            xs[(cf * 4 + 2) * 36 + rf] = (fmaxf(v.z * scs[kcol + 2] + shs[kcol + 2], 0.f) + rv.z) * INVS;
            xs[(cf * 4 + 3) * 36 + rf] = (fmaxf(v.w * scs[kcol + 3] + shs[kcol + 3], 0.f) + rv.w) * INVS;
        }
        {
            int cc = (t & 15) * 4;
            int k = t >> 4;
            #pragma unroll
            for (int pass = 0; pass < 2; pass++, k += 16) {
                *(float4*)(bs + k * 64 + cc) = *(const float4*)(B + (k0 + k) * 64 + cc);
            }
        }
        __syncthreads();
        #pragma unroll 8
        for (int k = 0; k < 32; k++) {
            float2 av = *(const float2*)(xs + k * 36 + r0);
            float4 bv = *(const float4*)(bs + k * 64 + c0);
            acc[0][0] += av.x * bv.x; acc[0][1] += av.x * bv.y;
            acc[0][2] += av.x * bv.z; acc[0][3] += av.x * bv.w;
            acc[1][0] += av.y * bv.x; acc[1][1] += av.y * bv.y;
            acc[1][2] += av.y * bv.z; acc[1][3] += av.y * bv.w;
        }
    }
    float4 bv = *(const float4*)(bias + c0);
    #pragma unroll
    for (int i = 0; i < 2; i++) {
        int gr = row0 + r0 + i;
        float4 o = {acc[i][0] + bv.x, acc[i][1] + bv.y, acc[i][2] + bv.z, acc[i][3] + bv.w};
        *(float4*)(y + gr * 64 + c0) = o;
    }
}

// ---------------- fused mean-pool (sorted batch) + MLP head ----------------

__global__ __launch_bounds__(256) void k_pool_head(const float* __restrict__ x, const int* __restrict__ batch,
                                                   const float* __restrict__ Wh1, const float* __restrict__ bh1,
                                                   const float* __restrict__ Wh2, const float* __restrict__ bh2,
                                                   float* __restrict__ out) {
    const int g = blockIdx.x;
    const int t = threadIdx.x;
    int lo = 0, hi = N_NODES;
    while (lo < hi) { int mid = (lo + hi) >> 1; if (batch[mid] < g) lo = mid + 1; else hi = mid; }
    int start = lo;
    hi = N_NODES;
    while (lo < hi) { int mid = (lo + hi) >> 1; if (batch[mid] < g + 1) lo = mid + 1; else hi = mid; }
    int end = lo;
    float cnt = (float)(end - start);

    __shared__ float part[256];
    __shared__ float p[64];
    __shared__ float hrow[256];
    const int c = t & 63;
    float s = 0.f;
    for (int r = start + (t >> 6); r < end; r += 4) s += x[r * 64 + c];
    part[t] = s;
    __syncthreads();
    if (t < 64) {
        float v = part[t] + part[t + 64] + part[t + 128] + part[t + 192];
        p[t] = v / fmaxf(cnt, 1.f);
    }
    __syncthreads();
    float a = bh1[t];
    #pragma unroll 8
    for (int k = 0; k < 64; k++) a += p[k] * Wh1[k * 256 + t];
    hrow[t] = fmaxf(a, 0.f);
    __syncthreads();
    if (t < 128) {
        float o = bh2[t];
        #pragma unroll 8
        for (int k = 0; k < 256; k++) o += hrow[k] * Wh2[k * 128 + t];
        out[g * 128 + t] = o;
    }
}

// ---------------- host ----------------

extern "C" void kernel_launch(void* const* d_in, const int* in_sizes, int n_in,
                              void* d_out, int out_size, void* d_ws, size_t ws_size,
                              hipStream_t stream) {
    (void)in_sizes; (void)n_in; (void)out_size; (void)ws_size;
    const float* x0 = (const float*)d_in[0];
    const int* ei = (const int*)d_in[1];
    const int* batch = (const int*)d_in[2];
    const float* Wh1 = (const float*)d_in[35];
    const float* bh1 = (const float*)d_in[36];
    const float* Wh2 = (const float*)d_in[37];
    const float* bh2 = (const float*)d_in[38];

    char* p = (char*)d_ws;
    auto alloc = [&](size_t bytes) -> void* {
        void* r = (void*)p;
        p += (bytes + 255) & ~(size_t)255;
        return r;
    };
    int* counts = (int*)alloc((size_t)N_NODES * 4);
    float* bnsum = (float*)alloc(2048);
    float* bnsq = bnsum + 256;
    int* bncnt = (int*)alloc(256);
    const size_t zero_bytes = (((size_t)N_NODES * 4 + 255) & ~(size_t)255) + 2048 + 256;
    int* offs = (int*)alloc((size_t)(N_NODES + 1) * 4);
    int* cursor = (int*)alloc((size_t)N_NODES * 4);
    int* csr_src = (int*)alloc((size_t)ETOT * 4);
    float* alS = (float*)alloc((size_t)N_NODES * 4 * 4);
    float* alD = (float*)alloc((size_t)N_NODES * 4 * 4);
    float* alSp = (float*)alloc((size_t)N_NODES * 16 * 4);
    float* alDp = (float*)alloc((size_t)N_NODES * 16 * 4);
    float* scaleb = (float*)alloc(1024);
    float* shiftb = (float*)alloc(1024);
    unsigned short* hbuf = (unsigned short*)alloc((size_t)N_NODES * 256 * 2);
    float* obuf = (float*)alloc((size_t)N_NODES * 256 * 4);
    float* rbuf = (float*)alloc((size_t)N_NODES * 256 * 4);
    float* xout = (float*)alloc((size_t)N_NODES * 64 * 4);
    unsigned short* Bf2_0 = (unsigned short*)alloc(256 * 256 * 2);  // W2 block0
    unsigned short* Bf2_1 = (unsigned short*)alloc(256 * 256 * 2);  // W2 block1
    unsigned short* Bf1_0 = (unsigned short*)alloc(64 * 256 * 2);   // W1 block0
    unsigned short* Bfr_0 = (unsigned short*)alloc(64 * 256 * 2);   // Wr block0
    unsigned short* Bf1_1 = (unsigned short*)alloc(64 * 256 * 2);   // W1 block1
    unsigned short* Bfr_1 = (unsigned short*)alloc(64 * 256 * 2);   // Wr block1

    // --- CSR by dst + weight fragment pre-pack ---
    hipMemsetAsync(counts, 0, zero_bytes, stream);
    k_hist<<<(ETOT + 255) / 256, 256, 0, stream>>>(ei, counts);
    k_scan<<<1, 1024, 0, stream>>>(counts, offs, cursor);
    k_scatter<<<(ETOT + 255) / 256, 256, 0, stream>>>(ei, cursor, csr_src);
    k_prepB<<<32, 256, 0, stream>>>((const float*)d_in[3 + 6], Bf2_0, 8192);
    k_prepB<<<32, 256, 0, stream>>>((const float*)d_in[19 + 6], Bf2_1, 8192);
    k_prepB<<<8, 256, 0, stream>>>((const float*)d_in[3 + 0], Bf1_0, 2048);
    k_prepB<<<8, 256, 0, stream>>>((const float*)d_in[3 + 12], Bfr_0, 2048);
    k_prepB<<<8, 256, 0, stream>>>((const float*)d_in[19 + 0], Bf1_1, 2048);
    k_prepB<<<8, 256, 0, stream>>>((const float*)d_in[19 + 12], Bfr_1, 2048);

    const int tile64_blocks = ((N_NODES + 63) / 64) * 4;  // 1252
    const int node_blocks = (N_NODES + 3) / 4;            // 5000
    const int red_blocks = (N_NODES + 255) / 256;
    const int final_blocks = N_NODES / 32;                // 625

    auto run_block = [&](const float* xin, int base, const unsigned short* Bf2,
                         const unsigned short* Bf1, const unsigned short* Bfr) {
        const float* a1s = (const float*)d_in[base + 1];
        const float* a1d = (const float*)d_in[base + 2];
        const float* b1 = (const float*)d_in[base + 3];
        const float* g1 = (const float*)d_in[base + 4];
        const float* be1 = (const float*)d_in[base + 5];
        const float* a2s = (const float*)d_in[base + 7];
        const float* a2d = (const float*)d_in[base + 8];
        const float* b2 = (const float*)d_in[base + 9];
        const float* g2 = (const float*)d_in[base + 10];
        const float* be2 = (const float*)d_in[base + 11];
        const float* br = (const float*)d_in[base + 13];
        const float* Wf = (const float*)d_in[base + 14];
        const float* bf = (const float*)d_in[base + 15];

        k_gemm64_dual<<<tile64_blocks, 256, 0, stream>>>(xin, Bf1, Bfr, br, a1s, a1d, hbuf, rbuf, alS, alD);
        k_agg<4><<<node_blocks, 256, 0, stream>>>(hbuf, alS, alD, offs, csr_src, b1, obuf);
        k_bnstats_fin<<<256, 256, 0, stream>>>(obuf, bnsum, bnsq, g1, be1, scaleb, shiftb, bncnt);
        k_gemm256_mfma<<<tile64_blocks, 256, 0, stream>>>(obuf, scaleb, shiftb, Bf2, a2s, a2d, hbuf, alSp, alDp);
        k_alred<<<red_blocks, 256, 0, stream>>>(alSp, alDp, alS, alD);
        k_agg<1><<<node_blocks, 256, 0, stream>>>(hbuf, alS, alD, offs, csr_src, b2, obuf);
        k_bnstats_fin<<<256, 256, 0, stream>>>(obuf, bnsum, bnsq, g2, be2, scaleb, shiftb, bncnt);
        k_gemm_final<<<final_blocks, 256, 0, stream>>>(obuf, scaleb, shiftb, rbuf, Wf, bf, xout);
    };

    run_block(x0, 3, Bf2_0, Bf1_0, Bfr_0);
    run_block(xout, 19, Bf2_1, Bf1_1, Bfr_1);

    k_pool_head<<<G_GROUPS, 256, 0, stream>>>(xout, batch, Wh1, bh1, Wh2, bh2, (float*)d_out);
}

// Round 14
// 626.947 us; speedup vs baseline: 1.1782x; 1.0115x over previous
//
#include <hip/hip_runtime.h>

#define N_NODES 20000
#define N_EDGES 320000
#define ETOT (N_EDGES + N_NODES)
#define G_GROUPS 64

typedef __attribute__((ext_vector_type(8))) short bf16x8;
typedef __attribute__((ext_vector_type(4))) float f32x4;

// bf16 helpers (RNE)
__device__ __forceinline__ unsigned short f2bf(float f) {
    unsigned int u = __float_as_uint(f);
    u += 0x7fffu + ((u >> 16) & 1u);
    return (unsigned short)(u >> 16);
}
__device__ __forceinline__ float bf2f(unsigned short v) {
    return __uint_as_float(((unsigned int)v) << 16);
}
__device__ __forceinline__ unsigned int pack2bf(float a, float b) {
    return (unsigned int)f2bf(a) | ((unsigned int)f2bf(b) << 16);
}

// ---------------- CSR build ----------------

__global__ __launch_bounds__(256) void k_hist(const int* __restrict__ ei, int* __restrict__ counts) {
    int e = blockIdx.x * 256 + threadIdx.x;
    if (e >= ETOT) return;
    int dst = (e < N_EDGES) ? ei[N_EDGES + e] : (e - N_EDGES);
    atomicAdd(&counts[dst], 1);
}

__global__ __launch_bounds__(1024) void k_scan(const int* __restrict__ counts, int* __restrict__ offs,
                                               int* __restrict__ cursor) {
    __shared__ int sdata[1024];
    const int t = threadIdx.x;
    const int chunk = (N_NODES + 1023) / 1024;  // 20
    int base = t * chunk;
    int s = 0;
    for (int i = 0; i < chunk; i++) { int idx = base + i; if (idx < N_NODES) s += counts[idx]; }
    sdata[t] = s;
    __syncthreads();
    for (int off = 1; off < 1024; off <<= 1) {
        int v = (t >= off) ? sdata[t - off] : 0;
        __syncthreads();
        sdata[t] += v;
        __syncthreads();
    }
    int prefix = (t == 0) ? 0 : sdata[t - 1];
    for (int i = 0; i < chunk; i++) {
        int idx = base + i;
        if (idx < N_NODES) {
            int cv = counts[idx];
            offs[idx] = prefix;
            cursor[idx] = prefix;
            prefix += cv;
        }
    }
    if (t == 1023) offs[N_NODES] = sdata[1023];
}

__global__ __launch_bounds__(256) void k_scatter(const int* __restrict__ ei, int* __restrict__ cursor,
                                                 int* __restrict__ csr_src) {
    int e = blockIdx.x * 256 + threadIdx.x;
    if (e >= ETOT) return;
    int src = (e < N_EDGES) ? ei[e] : (e - N_EDGES);
    int dst = (e < N_EDGES) ? ei[N_EDGES + e] : (e - N_EDGES);
    int p = atomicAdd(&cursor[dst], 1);
    csr_src[p] = src;
}

// ---------------- pre-pack all weights -> B-fragment-major bf16, ONE dispatch ----------------
// frag s: l=s&63, nt=(s>>6)&15, kt=s>>10; Bf[s*8+j] = bf16(W[(kt*32+(l>>4)*8+j)*256 + nt*16+(l&15)])
// blocks: [0,32) W2a, [32,64) W2b, [64,72) W1a, [72,80) Wra, [80,88) W1b, [88,96) Wrb

__global__ __launch_bounds__(256) void k_prepB_all(const float* __restrict__ W2a, const float* __restrict__ W2b,
                                                   const float* __restrict__ W1a, const float* __restrict__ Wra,
                                                   const float* __restrict__ W1b, const float* __restrict__ Wrb,
                                                   unsigned short* __restrict__ B2a, unsigned short* __restrict__ B2b,
                                                   unsigned short* __restrict__ B1a, unsigned short* __restrict__ Bra,
                                                   unsigned short* __restrict__ B1b, unsigned short* __restrict__ Brb) {
    int b = blockIdx.x;
    const float* W;
    unsigned short* Bf;
    int s0;
    if (b < 32) { W = W2a; Bf = B2a; s0 = b; }
    else if (b < 64) { W = W2b; Bf = B2b; s0 = b - 32; }
    else if (b < 72) { W = W1a; Bf = B1a; s0 = b - 64; }
    else if (b < 80) { W = Wra; Bf = Bra; s0 = b - 72; }
    else if (b < 88) { W = W1b; Bf = B1b; s0 = b - 80; }
    else { W = Wrb; Bf = Brb; s0 = b - 88; }
    int s = s0 * 256 + threadIdx.x;
    int l = s & 63;
    int nt = (s >> 6) & 15;
    int kt = s >> 10;
    int n = nt * 16 + (l & 15);
    int kb = kt * 32 + (l >> 4) * 8;
    float v[8];
    #pragma unroll
    for (int j = 0; j < 8; j++) v[j] = W[(kb + j) * 256 + n];
    uint4 q = {pack2bf(v[0], v[1]), pack2bf(v[2], v[3]), pack2bf(v[4], v[5]), pack2bf(v[6], v[7])};
    *(uint4*)(Bf + s * 8) = q;
}

// ---------------- MFMA dual GEMM [N,64]x[64,256] (W1 & Wr), alpha fused ----------------

__global__ __launch_bounds__(256) void k_gemm64_dual(const float* __restrict__ x,
                                                     const unsigned short* __restrict__ Bf1,
                                                     const unsigned short* __restrict__ Bfr,
                                                     const float* __restrict__ br,
                                                     const float* __restrict__ a_s, const float* __restrict__ a_d,
                                                     unsigned short* __restrict__ hbf, float* __restrict__ res,
                                                     float* __restrict__ alS, float* __restrict__ alD) {
    const int rb = blockIdx.x >> 2, cs = blockIdx.x & 3;
    const int row0 = rb * 64;
    const int nrows = min(64, N_NODES - row0);
    const int t = threadIdx.x;
    const int w = t >> 6;
    const int l = t & 63;
    const int quad = l >> 4;
    const int colLocal = l & 15;
    __shared__ unsigned short As[8 * 64 * 8];  // 8 KB
    __shared__ float alsm[4][64], aldm[4][64];

    const int ntg = cs * 4 + w;
    bf16x8 b1f[2], brf[2];
    #pragma unroll
    for (int kt = 0; kt < 2; kt++) {
        b1f[kt] = *(const bf16x8*)(Bf1 + ((kt * 16 + ntg) * 64 + l) * 8);
        brf[kt] = *(const bf16x8*)(Bfr + ((kt * 16 + ntg) * 64 + l) * 8);
    }

    #pragma unroll
    for (int gi = 0; gi < 2; gi++) {
        int g = 2 * w + gi;
        int kt = g >> 2, mt = g & 3;
        int sm = mt * 16 + (l & 15);
        int koff = kt * 32 + (l >> 4) * 8;
        float4 v0 = {0.f, 0.f, 0.f, 0.f}, v1 = {0.f, 0.f, 0.f, 0.f};
        if (sm < nrows) {
            v0 = *(const float4*)(x + (row0 + sm) * 64 + koff);
            v1 = *(const float4*)(x + (row0 + sm) * 64 + koff + 4);
        }
        uint4 q = {pack2bf(v0.x, v0.y), pack2bf(v0.z, v0.w), pack2bf(v1.x, v1.y), pack2bf(v1.z, v1.w)};
        *(uint4*)(As + (g * 64 + l) * 8) = q;
    }
    __syncthreads();

    f32x4 acc1[4], acc2[4];
    #pragma unroll
    for (int mt = 0; mt < 4; mt++) {
        acc1[mt] = (f32x4){0.f, 0.f, 0.f, 0.f};
        acc2[mt] = (f32x4){0.f, 0.f, 0.f, 0.f};
    }
    #pragma unroll
    for (int kt = 0; kt < 2; kt++) {
        #pragma unroll
        for (int mt = 0; mt < 4; mt++) {
            bf16x8 af = *(const bf16x8*)(As + ((kt * 4 + mt) * 64 + l) * 8);
            acc1[mt] = __builtin_amdgcn_mfma_f32_16x16x32_bf16(af, b1f[kt], acc1[mt], 0, 0, 0);
            acc2[mt] = __builtin_amdgcn_mfma_f32_16x16x32_bf16(af, brf[kt], acc2[mt], 0, 0, 0);
        }
    }

    const int col = cs * 64 + w * 16 + colLocal;
    const float brv = br[col];
    const float asv = a_s[col];
    const float adv = a_d[col];
    #pragma unroll
    for (int mt = 0; mt < 4; mt++) {
        #pragma unroll
        for (int r = 0; r < 4; r++) {
            float v1 = acc1[mt][r];
            int lr = mt * 16 + quad * 4 + r;
            bool ok = lr < nrows;
            int row = row0 + lr;
            if (ok) {
                hbf[row * 256 + col] = f2bf(v1);
                res[row * 256 + col] = acc2[mt][r] + brv;
            }
            float ps = v1 * asv, pd = v1 * adv;
            #pragma unroll
            for (int off = 1; off < 16; off <<= 1) {
                ps += __shfl_xor(ps, off);
                pd += __shfl_xor(pd, off);
            }
            if (colLocal == 0) {
                alsm[w][lr] = ps;
                aldm[w][lr] = pd;
            }
        }
    }
    __syncthreads();
    if (t < 64 && t < nrows) {
        float s = (alsm[0][t] + alsm[1][t]) + (alsm[2][t] + alsm[3][t]);
        float d = (aldm[0][t] + aldm[1][t]) + (aldm[2][t] + aldm[3][t]);
        alS[(row0 + t) * 4 + cs] = s;
        alD[(row0 + t) * 4 + cs] = d;
    }
}

// ---------------- CSR softmax-aggregation, SCALAR index/logit loads, 1 VMEM/edge ----------------
// readfirstlane(node) marks the whole index chain wave-uniform: offs/csr_src/alS rows
// become s_load (SMEM pipe); only the h-row gather stays VMEM.

template <int H>
__global__ __launch_bounds__(256) void k_agg(const unsigned short* __restrict__ hbf, const float* __restrict__ alS,
                                             const float* __restrict__ alD, const int* __restrict__ offs,
                                             const int* __restrict__ csr_src, const float* __restrict__ bias,
                                             float* __restrict__ out) {
    const int node = __builtin_amdgcn_readfirstlane(blockIdx.x * 4 + (threadIdx.x >> 6));  // grid exact: 5000*4
    const int lane = threadIdx.x & 63;
    const int head = (H == 4) ? (lane >> 4) : 0;
    float ald;
    if (H == 4) {
        float4 d4 = *(const float4*)(alD + node * 4);  // scalar dwordx4
        ald = (head == 0) ? d4.x : (head == 1) ? d4.y : (head == 2) ? d4.z : d4.w;
    } else {
        ald = alD[node];
    }
    const int e0 = offs[node], e1 = offs[node + 1];
    const unsigned short* hp = hbf + lane * 4;
    float den = 0.f, a0 = 0.f, a1 = 0.f, a2 = 0.f, a3 = 0.f;
    int e = e0;
    for (; e + 8 <= e1; e += 8) {
        int s[8];
        #pragma unroll
        for (int i = 0; i < 8; i++) s[i] = csr_src[e + i];  // s_load (uniform)
        ushort4 hq[8];
        #pragma unroll
        for (int i = 0; i < 8; i++) hq[i] = *(const ushort4*)(hp + s[i] * 256);  // the one VMEM gather
        float w[8];
        #pragma unroll
        for (int i = 0; i < 8; i++) {
            float v;
            if (H == 4) {
                float4 s4 = *(const float4*)(alS + s[i] * 4);  // scalar dwordx4
                float as = (head == 0) ? s4.x : (head == 1) ? s4.y : (head == 2) ? s4.z : s4.w;
                v = as + ald;
            } else {
                v = alS[s[i]] + ald;  // scalar
            }
            v = (v > 0.f) ? v : 0.2f * v;
            w[i] = __expf(v);
        }
        #pragma unroll
        for (int i = 0; i < 8; i++) {
            den += w[i];
            a0 += w[i] * bf2f(hq[i].x); a1 += w[i] * bf2f(hq[i].y);
            a2 += w[i] * bf2f(hq[i].z); a3 += w[i] * bf2f(hq[i].w);
        }
    }
    for (; e < e1; e++) {
        int s = csr_src[e];
        float v;
        if (H == 4) {
            float4 s4 = *(const float4*)(alS + s * 4);
            float as = (head == 0) ? s4.x : (head == 1) ? s4.y : (head == 2) ? s4.z : s4.w;
            v = as + ald;
        } else {
            v = alS[s] + ald;
        }
        v = (v > 0.f) ? v : 0.2f * v;
        float w = __expf(v);
        ushort4 hq = *(const ushort4*)(hp + s * 256);
        den += w;
        a0 += w * bf2f(hq.x); a1 += w * bf2f(hq.y); a2 += w * bf2f(hq.z); a3 += w * bf2f(hq.w);
    }
    float inv = 1.f / den;
    const float4 bv = *(const float4*)(bias + lane * 4);
    float4 o = {a0 * inv + bv.x, a1 * inv + bv.y, a2 * inv + bv.z, a3 * inv + bv.w};
    *(float4*)(out + node * 256 + lane * 4) = o;
}

// ---------------- BatchNorm: stats + finalize fused (last-block-done) + optional zeroing ----------------

__global__ __launch_bounds__(256) void k_bnstats_fin(const float* __restrict__ x, float* __restrict__ sum,
                                                     float* __restrict__ sumsq, const float* __restrict__ g,
                                                     const float* __restrict__ be, float* __restrict__ scale,
                                                     float* __restrict__ shift, int* __restrict__ counter,
                                                     float* __restrict__ zS, float* __restrict__ zD) {
    const int c = threadIdx.x;
    if (zS) {  // zero next-stage alpha accumulators (for gemm256's atomics)
        int idx = blockIdx.x * 256 + c;
        if (idx < N_NODES) { zS[idx] = 0.f; zD[idx] = 0.f; }
    }
    float s = 0.f, q = 0.f;
    for (int r = blockIdx.x; r < N_NODES; r += gridDim.x) {
        float v = x[r * 256 + c];
        s += v; q += v * v;
    }
    atomicAdd(&sum[c], s);
    atomicAdd(&sumsq[c], q);
    __threadfence();
    __syncthreads();
    __shared__ int lastFlag;
    if (c == 0) lastFlag = (atomicAdd(counter, 1) == (int)gridDim.x - 1);
    __syncthreads();
    if (lastFlag) {
        float S = atomicAdd(&sum[c], 0.f);
        float Q = atomicAdd(&sumsq[c], 0.f);
        float mu = S * (1.f / N_NODES);
        float var = Q * (1.f / N_NODES) - mu * mu;
        float sc = g[c] * rsqrtf(var + 1e-5f);
        scale[c] = sc;
        shift[c] = be[c] - mu * sc;
        sum[c] = 0.f;
        sumsq[c] = 0.f;
        if (c == 0) *counter = 0;
    }
}

// ---------------- MFMA GEMM: bf16(relu(bn(A))) @ bf16(W2), alpha via atomics (no alred) ----------------

__global__ __launch_bounds__(256) void k_gemm256_mfma(const float* __restrict__ A, const float* __restrict__ scale,
                                                      const float* __restrict__ shift,
                                                      const unsigned short* __restrict__ Bf,
                                                      const float* __restrict__ a_s, const float* __restrict__ a_d,
                                                      unsigned short* __restrict__ C, float* __restrict__ alS2,
                                                      float* __restrict__ alD2) {
    const int rb = blockIdx.x >> 2, cs = blockIdx.x & 3;
    const int row0 = rb * 64;
    const int nrows = min(64, N_NODES - row0);
    const int t = threadIdx.x;
    const int w = t >> 6;
    const int l = t & 63;
    const int quad = l >> 4;
    const int colLocal = l & 15;
    __shared__ unsigned short As[2 * 4 * 64 * 8];  // 8 KB
    __shared__ float scs[256], shs[256];
    scs[t] = scale[t];
    shs[t] = shift[t];

    const int ntg = cs * 4 + w;
    bf16x8 bfrag[8];
    #pragma unroll
    for (int kt = 0; kt < 8; kt++)
        bfrag[kt] = *(const bf16x8*)(Bf + ((kt * 16 + ntg) * 64 + l) * 8);

    f32x4 acc[4];
    #pragma unroll
    for (int mt = 0; mt < 4; mt++) acc[mt] = (f32x4){0.f, 0.f, 0.f, 0.f};

    const int smt = (t >> 6) & 3;
    const int sm = smt * 16 + (l & 15);
    const int skoff = (l >> 4) * 8;

    for (int kc = 0; kc < 4; kc++) {
        __syncthreads();
        #pragma unroll
        for (int kt2 = 0; kt2 < 2; kt2++) {
            int k = kc * 64 + kt2 * 32 + skoff;
            float4 v0 = {0.f, 0.f, 0.f, 0.f}, v1 = {0.f, 0.f, 0.f, 0.f};
            if (sm < nrows) {
                v0 = *(const float4*)(A + (row0 + sm) * 256 + k);
                v1 = *(const float4*)(A + (row0 + sm) * 256 + k + 4);
                v0.x = fmaxf(v0.x * scs[k + 0] + shs[k + 0], 0.f);
                v0.y = fmaxf(v0.y * scs[k + 1] + shs[k + 1], 0.f);
                v0.z = fmaxf(v0.z * scs[k + 2] + shs[k + 2], 0.f);
                v0.w = fmaxf(v0.w * scs[k + 3] + shs[k + 3], 0.f);
                v1.x = fmaxf(v1.x * scs[k + 4] + shs[k + 4], 0.f);
                v1.y = fmaxf(v1.y * scs[k + 5] + shs[k + 5], 0.f);
                v1.z = fmaxf(v1.z * scs[k + 6] + shs[k + 6], 0.f);
                v1.w = fmaxf(v1.w * scs[k + 7] + shs[k + 7], 0.f);
            }
            uint4 q = {pack2bf(v0.x, v0.y), pack2bf(v0.z, v0.w), pack2bf(v1.x, v1.y), pack2bf(v1.z, v1.w)};
            *(uint4*)(As + ((kt2 * 4 + smt) * 64 + l) * 8) = q;
        }
        __syncthreads();
        #pragma unroll
        for (int kt2 = 0; kt2 < 2; kt2++) {
            int ktg = kc * 2 + kt2;
            #pragma unroll
            for (int mt = 0; mt < 4; mt++) {
                bf16x8 af = *(const bf16x8*)(As + ((kt2 * 4 + mt) * 64 + l) * 8);
                acc[mt] = __builtin_amdgcn_mfma_f32_16x16x32_bf16(af, bfrag[ktg], acc[mt], 0, 0, 0);
            }
        }
    }

    const int col = cs * 64 + w * 16 + colLocal;
    const float asv = a_s[col];
    const float adv = a_d[col];
    #pragma unroll
    for (int mt = 0; mt < 4; mt++) {
        #pragma unroll
        for (int r = 0; r < 4; r++) {
            float v = acc[mt][r];
            int lr = mt * 16 + quad * 4 + r;
            bool ok = lr < nrows;
            int row = row0 + lr;
            if (ok) C[row * 256 + col] = f2bf(v);
            float ps = v * asv, pd = v * adv;
            #pragma unroll
            for (int off = 1; off < 16; off <<= 1) {
                ps += __shfl_xor(ps, off);
                pd += __shfl_xor(pd, off);
            }
            if (colLocal == 0 && ok) {
                atomicAdd(&alS2[row], ps);
                atomicAdd(&alD2[row], pd);
            }
        }
    }
}

// ---------------- final GEMM ((relu(bn(A))+res)*invsqrt2)@Wf+bf -> [N,64], 32x64 tiles ----------------

__global__ __launch_bounds__(256) void k_gemm_final(const float* __restrict__ A, const float* __restrict__ scale,
                                                    const float* __restrict__ shift, const float* __restrict__ res,
                                                    const float* __restrict__ B, const float* __restrict__ bias,
                                                    float* __restrict__ y) {
    const int row0 = blockIdx.x * 32;
    const int t = threadIdx.x;
    const float INVS = 0.70710678118654752440f;
    __shared__ float xs[32 * 36];
    __shared__ float bs[32 * 64];
    __shared__ float scs[256], shs[256];
    scs[t] = scale[t];
    shs[t] = shift[t];
    const int rf = (t & 15) | ((t >> 7) << 4);
    const int cf = (t >> 4) & 7;
    const int c0 = (t & 15) * 4;
    const int r0 = (t >> 4) * 2;
    float acc[2][4] = {};
    for (int k0 = 0; k0 < 256; k0 += 32) {
        __syncthreads();
        {
            int kcol = k0 + cf * 4;
            int gi = (row0 + rf) * 256 + kcol;
            float4 v = *(const float4*)(A + gi);
            float4 rv = *(const float4*)(res + gi);
            xs[(cf * 4 + 0) * 36 + rf] = (fmaxf(v.x * scs[kcol + 0] + shs[kcol + 0], 0.f) + rv.x) * INVS;
            xs[(cf * 4 + 1) * 36 + rf] = (fmaxf(v.y * scs[kcol + 1] + shs[kcol + 1], 0.f) + rv.y) * INVS;
            xs[(cf * 4 + 2) * 36 + rf] = (fmaxf(v.z * scs[kcol + 2] + shs[kcol + 2], 0.f) + rv.z) * INVS;
            xs[(cf * 4 + 3) * 36 + rf] = (fmaxf(v.w * scs[kcol + 3] + shs[kcol + 3], 0.f) + rv.w) * INVS;
        }
        {
            int cc = (t & 15) * 4;
            int k = t >> 4;
            #pragma unroll
            for (int pass = 0; pass < 2; pass++, k += 16) {
                *(float4*)(bs + k * 64 + cc) = *(const float4*)(B + (k0 + k) * 64 + cc);
            }
        }
        __syncthreads();
        #pragma unroll 8
        for (int k = 0; k < 32; k++) {
            float2 av = *(const float2*)(xs + k * 36 + r0);
            float4 bv = *(const float4*)(bs + k * 64 + c0);
            acc[0][0] += av.x * bv.x; acc[0][1] += av.x * bv.y;
            acc[0][2] += av.x * bv.z; acc[0][3] += av.x * bv.w;
            acc[1][0] += av.y * bv.x; acc[1][1] += av.y * bv.y;
            acc[1][2] += av.y * bv.z; acc[1][3] += av.y * bv.w;
        }
    }
    float4 bv = *(const float4*)(bias + c0);
    #pragma unroll
    for (int i = 0; i < 2; i++) {
        int gr = row0 + r0 + i;
        float4 o = {acc[i][0] + bv.x, acc[i][1] + bv.y, acc[i][2] + bv.z, acc[i][3] + bv.w};
        *(float4*)(y + gr * 64 + c0) = o;
    }
}

// ---------------- fused mean-pool (sorted batch) + MLP head ----------------

__global__ __launch_bounds__(256) void k_pool_head(const float* __restrict__ x, const int* __restrict__ batch,
                                                   const float* __restrict__ Wh1, const float* __restrict__ bh1,
                                                   const float* __restrict__ Wh2, const float* __restrict__ bh2,
                                                   float* __restrict__ out) {
    const int g = blockIdx.x;
    const int t = threadIdx.x;
    int lo = 0, hi = N_NODES;
    while (lo < hi) { int mid = (lo + hi) >> 1; if (batch[mid] < g) lo = mid + 1; else hi = mid; }
    int start = lo;
    hi = N_NODES;
    while (lo < hi) { int mid = (lo + hi) >> 1; if (batch[mid] < g + 1) lo = mid + 1; else hi = mid; }
    int end = lo;
    float cnt = (float)(end - start);

    __shared__ float part[256];
    __shared__ float p[64];
    __shared__ float hrow[256];
    const int c = t & 63;
    float s = 0.f;
    for (int r = start + (t >> 6); r < end; r += 4) s += x[r * 64 + c];
    part[t] = s;
    __syncthreads();
    if (t < 64) {
        float v = part[t] + part[t + 64] + part[t + 128] + part[t + 192];
        p[t] = v / fmaxf(cnt, 1.f);
    }
    __syncthreads();
    float a = bh1[t];
    #pragma unroll 8
    for (int k = 0; k < 64; k++) a += p[k] * Wh1[k * 256 + t];
    hrow[t] = fmaxf(a, 0.f);
    __syncthreads();
    if (t < 128) {
        float o = bh2[t];
        #pragma unroll 8
        for (int k = 0; k < 256; k++) o += hrow[k] * Wh2[k * 128 + t];
        out[g * 128 + t] = o;
    }
}

// ---------------- host ----------------

extern "C" void kernel_launch(void* const* d_in, const int* in_sizes, int n_in,
                              void* d_out, int out_size, void* d_ws, size_t ws_size,
                              hipStream_t stream) {
    (void)in_sizes; (void)n_in; (void)out_size; (void)ws_size;
    const float* x0 = (const float*)d_in[0];
    const int* ei = (const int*)d_in[1];
    const int* batch = (const int*)d_in[2];
    const float* Wh1 = (const float*)d_in[35];
    const float* bh1 = (const float*)d_in[36];
    const float* Wh2 = (const float*)d_in[37];
    const float* bh2 = (const float*)d_in[38];

    char* p = (char*)d_ws;
    auto alloc = [&](size_t bytes) -> void* {
        void* r = (void*)p;
        p += (bytes + 255) & ~(size_t)255;
        return r;
    };
    int* counts = (int*)alloc((size_t)N_NODES * 4);
    float* bnsum = (float*)alloc(2048);
    float* bnsq = bnsum + 256;
    int* bncnt = (int*)alloc(256);
    const size_t zero_bytes = (((size_t)N_NODES * 4 + 255) & ~(size_t)255) + 2048 + 256;
    int* offs = (int*)alloc((size_t)(N_NODES + 1) * 4);
    int* cursor = (int*)alloc((size_t)N_NODES * 4);
    int* csr_src = (int*)alloc((size_t)ETOT * 4);
    float* alS = (float*)alloc((size_t)N_NODES * 4 * 4);   // H=4 logits [node][4]
    float* alD = (float*)alloc((size_t)N_NODES * 4 * 4);
    float* alS2 = (float*)alloc((size_t)N_NODES * 4);      // H=1 logits (atomic-accumulated)
    float* alD2 = (float*)alloc((size_t)N_NODES * 4);
    float* scaleb = (float*)alloc(1024);
    float* shiftb = (float*)alloc(1024);
    unsigned short* hbuf = (unsigned short*)alloc((size_t)N_NODES * 256 * 2);
    float* obuf = (float*)alloc((size_t)N_NODES * 256 * 4);
    float* rbuf = (float*)alloc((size_t)N_NODES * 256 * 4);
    float* xout = (float*)alloc((size_t)N_NODES * 64 * 4);
    unsigned short* Bf2_0 = (unsigned short*)alloc(256 * 256 * 2);
    unsigned short* Bf2_1 = (unsigned short*)alloc(256 * 256 * 2);
    unsigned short* Bf1_0 = (unsigned short*)alloc(64 * 256 * 2);
    unsigned short* Bfr_0 = (unsigned short*)alloc(64 * 256 * 2);
    unsigned short* Bf1_1 = (unsigned short*)alloc(64 * 256 * 2);
    unsigned short* Bfr_1 = (unsigned short*)alloc(64 * 256 * 2);

    // --- CSR by dst + weight fragment pre-pack (one dispatch) ---
    hipMemsetAsync(counts, 0, zero_bytes, stream);
    k_hist<<<(ETOT + 255) / 256, 256, 0, stream>>>(ei, counts);
    k_scan<<<1, 1024, 0, stream>>>(counts, offs, cursor);
    k_scatter<<<(ETOT + 255) / 256, 256, 0, stream>>>(ei, cursor, csr_src);
    k_prepB_all<<<96, 256, 0, stream>>>((const float*)d_in[3 + 6], (const float*)d_in[19 + 6],
                                        (const float*)d_in[3 + 0], (const float*)d_in[3 + 12],
                                        (const float*)d_in[19 + 0], (const float*)d_in[19 + 12],
                                        Bf2_0, Bf2_1, Bf1_0, Bfr_0, Bf1_1, Bfr_1);

    const int tile64_blocks = ((N_NODES + 63) / 64) * 4;  // 1252
    const int node_blocks = N_NODES / 4;                  // 5000 (exact)
    const int final_blocks = N_NODES / 32;                // 625

    auto run_block = [&](const float* xin, int base, const unsigned short* Bf2,
                         const unsigned short* Bf1, const unsigned short* Bfr) {
        const float* a1s = (const float*)d_in[base + 1];
        const float* a1d = (const float*)d_in[base + 2];
        const float* b1 = (const float*)d_in[base + 3];
        const float* g1 = (const float*)d_in[base + 4];
        const float* be1 = (const float*)d_in[base + 5];
        const float* a2s = (const float*)d_in[base + 7];
        const float* a2d = (const float*)d_in[base + 8];
        const float* b2 = (const float*)d_in[base + 9];
        const float* g2 = (const float*)d_in[base + 10];
        const float* be2 = (const float*)d_in[base + 11];
        const float* br = (const float*)d_in[base + 13];
        const float* Wf = (const float*)d_in[base + 14];
        const float* bf = (const float*)d_in[base + 15];

        k_gemm64_dual<<<tile64_blocks, 256, 0, stream>>>(xin, Bf1, Bfr, br, a1s, a1d, hbuf, rbuf, alS, alD);
        k_agg<4><<<node_blocks, 256, 0, stream>>>(hbuf, alS, alD, offs, csr_src, b1, obuf);
        // BN1 + zero alS2/alD2 for gemm256's atomic alpha accumulation
        k_bnstats_fin<<<256, 256, 0, stream>>>(obuf, bnsum, bnsq, g1, be1, scaleb, shiftb, bncnt, alS2, alD2);
        k_gemm256_mfma<<<tile64_blocks, 256, 0, stream>>>(obuf, scaleb, shiftb, Bf2, a2s, a2d, hbuf, alS2, alD2);
        k_agg<1><<<node_blocks, 256, 0, stream>>>(hbuf, alS2, alD2, offs, csr_src, b2, obuf);
        k_bnstats_fin<<<256, 256, 0, stream>>>(obuf, bnsum, bnsq, g2, be2, scaleb, shiftb, bncnt, nullptr, nullptr);
        k_gemm_final<<<final_blocks, 256, 0, stream>>>(obuf, scaleb, shiftb, rbuf, Wf, bf, xout);
    };

    run_block(x0, 3, Bf2_0, Bf1_0, Bfr_0);
    run_block(xout, 19, Bf2_1, Bf1_1, Bfr_1);

    k_pool_head<<<G_GROUPS, 256, 0, stream>>>(xout, batch, Wh1, bh1, Wh2, bh2, (float*)d_out);
}